// Round 17
// baseline (296.837 us; speedup 1.0000x reference)
//
#include <hip/hip_runtime.h>
#include <math.h>

#define BB 8
#define TT 512
#define DD 256
#define DIM 512
#define KW 4
#define MM 2
#define HH 4
#define HDIM 64
#define LL 2
#define VV 272
#define RP (BB*TT + 128)   // padded row count for ip buffer

typedef __attribute__((ext_vector_type(8))) short bf16x8;
typedef __attribute__((ext_vector_type(4))) float f32x4;

__device__ __forceinline__ float sigf(float x){ return 1.f/(1.f+__expf(-x)); }
__device__ __forceinline__ float siluf(float x){ return x/(1.f+__expf(-x)); }

__device__ __forceinline__ unsigned short f2bf(float f){
  unsigned int u = __float_as_uint(f);
  unsigned int r = (u + 0x7FFFu + ((u >> 16) & 1u)) >> 16;
  return (unsigned short)r;
}
__device__ __forceinline__ float bf2f(unsigned short s){
  return __uint_as_float(((unsigned int)s) << 16);
}

// DPP reduces (no DS ops)
__device__ __forceinline__ float xor1_add(float x){
  int y = __builtin_amdgcn_update_dpp(0, __float_as_int(x), 0xB1, 0xF, 0xF, true);
  return x + __int_as_float(y);
}
__device__ __forceinline__ float xor2_add(float x){
  int y = __builtin_amdgcn_update_dpp(0, __float_as_int(x), 0x4E, 0xF, 0xF, true);
  return x + __int_as_float(y);
}
__device__ __forceinline__ float ror4_add(float x){
  int y = __builtin_amdgcn_update_dpp(0, __float_as_int(x), 0x124, 0xF, 0xF, true);
  return x + __int_as_float(y);
}
__device__ __forceinline__ float ror8_add(float x){
  int y = __builtin_amdgcn_update_dpp(0, __float_as_int(x), 0x128, 0xF, 0xF, true);
  return x + __int_as_float(y);
}

// async global->LDS, 16B per lane. LDS dest is wave-uniform base + lane*16.
__device__ __forceinline__ void gl_lds16(const void* g, void* l){
  __builtin_amdgcn_global_load_lds(
      (const __attribute__((address_space(1))) unsigned int*)g,
      (__attribute__((address_space(3))) unsigned int*)l,
      16, 0, 0);
}

// ---------------- weight convert + transpose to bf16 [N][K] ----------------
#define LWB 589824
__global__ void k_cvt(const float* __restrict__ Wup, const float* __restrict__ Wgate,
                      const float* __restrict__ Wdown, const float* __restrict__ Wv,
                      const float* __restrict__ Wout, const float* __restrict__ emb,
                      unsigned short* __restrict__ wbf){
  int idx = blockIdx.x*256 + threadIdx.x;
  if (idx >= 2*LWB + VV*DD) return;
  float v;
  if (idx < 2*LWB){
    int l = (idx >= LWB) ? 1 : 0;
    int local = idx - l*LWB;
    if (local < 131072){ int n = local>>8, k = local&255;
      v = Wup[(size_t)l*131072 + k*DIM + n]; }
    else if (local < 262144){ local -= 131072; int n = local>>8, k = local&255;
      v = Wgate[(size_t)l*131072 + k*DIM + n]; }
    else if (local < 393216){ local -= 262144; int n = local>>9, k = local&511;
      v = Wdown[(size_t)l*131072 + k*DD + n]; }
    else if (local < 524288){ local -= 393216; int n = local>>8, k = local&255;
      v = Wv[(size_t)l*131072 + k*DIM + n]; }
    else { local -= 524288; int n = local>>8, k = local&255;
      v = Wout[(size_t)l*65536 + k*DD + n]; }
  } else {
    v = emb[idx - 2*LWB];
  }
  wbf[idx] = f2bf(v);
}

// ------- fused embedding gather + rmsnorm (layer 0) ---
__global__ void __launch_bounds__(256) k_embed_norm(const int* __restrict__ ids,
                                                    const float* __restrict__ emb,
                                                    const float* __restrict__ w,
                                                    float* __restrict__ x,
                                                    unsigned short* __restrict__ out){
  const int wv = threadIdx.x >> 6, l = threadIdx.x & 63;
  const int row = blockIdx.x*4 + wv;
  float4 v = *(const float4*)&emb[(size_t)ids[row]*DD + l*4];
  *(float4*)&x[(size_t)row*DD + l*4] = v;
  float ss = v.x*v.x + v.y*v.y + v.z*v.z + v.w*v.w;
  #pragma unroll
  for (int o = 32; o > 0; o >>= 1) ss += __shfl_xor(ss, o, 64);
  float sc = rsqrtf(ss*(1.f/DD) + 1e-6f);
  float4 wvv = *(const float4*)&w[l*4];
  ushort4 r;
  r.x = f2bf(v.x*sc*wvv.x); r.y = f2bf(v.y*sc*wvv.y);
  r.z = f2bf(v.z*sc*wvv.z); r.w = f2bf(v.w*sc*wvv.w);
  *(ushort4*)&out[(size_t)row*DD + l*4] = r;
}

// ---------------- rmsnorm -> bf16 out, 4 rows/block ----------------
__global__ void __launch_bounds__(256) k_rmsnorm(const float* __restrict__ in,
                                                 const float* __restrict__ w,
                                                 unsigned short* __restrict__ out){
  const int wv = threadIdx.x >> 6, l = threadIdx.x & 63;
  const int row = blockIdx.x*4 + wv;
  float4 v = *(const float4*)&in[(size_t)row*DD + l*4];
  float ss = v.x*v.x + v.y*v.y + v.z*v.z + v.w*v.w;
  #pragma unroll
  for (int o = 32; o > 0; o >>= 1) ss += __shfl_xor(ss, o, 64);
  float sc = rsqrtf(ss*(1.f/DD) + 1e-6f);
  float4 wvv = *(const float4*)&w[l*4];
  ushort4 r;
  r.x = f2bf(v.x*sc*wvv.x); r.y = f2bf(v.y*sc*wvv.y);
  r.z = f2bf(v.z*sc*wvv.z); r.w = f2bf(v.w*sc*wvv.w);
  *(ushort4*)&out[(size_t)row*DD + l*4] = r;
}

// -------- bf16 GEMM 64x64 tile (4 waves) --------
template<int MODE>
__global__ void __launch_bounds__(256) k_gemm64(const unsigned short* __restrict__ A,
                                                const unsigned short* __restrict__ Bt,
                                                float* __restrict__ Cf,
                                                unsigned short* __restrict__ Cb,
                                                int N, int K){
  __shared__ unsigned short as[64][72];
  __shared__ unsigned short bs[64][72];
  const int tid = threadIdx.x;
  const int w = tid >> 6, l = tid & 63;
  const int m0 = blockIdx.y*64, n0 = blockIdx.x*64;
  const int ar = tid >> 2, ac = (tid & 3)*16;
  f32x4 acc[4] = {};
  for (int k0 = 0; k0 < K; k0 += 64){
    { const bf16x8* src = (const bf16x8*)&A[(size_t)(m0+ar)*K + k0 + ac];
      *(bf16x8*)&as[ar][ac]   = src[0];
      *(bf16x8*)&as[ar][ac+8] = src[1];
    }
    { int n = n0 + ar;
      bf16x8 z; z = (bf16x8)(short)0;
      bf16x8 b0 = z, b1 = z;
      if (n < N){
        const bf16x8* src = (const bf16x8*)&Bt[(size_t)n*K + k0 + ac];
        b0 = src[0]; b1 = src[1];
      }
      *(bf16x8*)&bs[ar][ac]   = b0;
      *(bf16x8*)&bs[ar][ac+8] = b1;
    }
    __syncthreads();
    const int mr = w*16 + (l & 15);
    const int kb = (l >> 4)*8;
    #pragma unroll
    for (int kc2 = 0; kc2 < 2; ++kc2){
      bf16x8 af = *(const bf16x8*)&as[mr][kc2*32 + kb];
      #pragma unroll
      for (int nt = 0; nt < 4; ++nt){
        bf16x8 bfr = *(const bf16x8*)&bs[nt*16 + (l & 15)][kc2*32 + kb];
        acc[nt] = __builtin_amdgcn_mfma_f32_16x16x32_bf16(af, bfr, acc[nt], 0, 0, 0);
      }
    }
    __syncthreads();
  }
  #pragma unroll
  for (int nt = 0; nt < 4; ++nt){
    int col = n0 + nt*16 + (l & 15);
    if (col < N){
      #pragma unroll
      for (int r = 0; r < 4; ++r){
        int row = m0 + w*16 + (l >> 4)*4 + r;
        if (MODE == 0 || MODE == 2) Cf[(size_t)row*N + col] = acc[nt][r];
        if (MODE == 1 || MODE == 2) Cb[(size_t)row*N + col] = f2bf(acc[nt][r]);
      }
    }
  }
}

// -------- bf16 GEMM 128x64 tile (4 waves) --------
template<int MODE>
__global__ void __launch_bounds__(256) k_gemm128(const unsigned short* __restrict__ A,
                                                 const unsigned short* __restrict__ Bt,
                                                 float* __restrict__ Cf,
                                                 unsigned short* __restrict__ Cb,
                                                 int N, int K){
  __shared__ unsigned short as[128][72];
  __shared__ unsigned short bs[64][72];
  const int tid = threadIdx.x;
  const int w = tid >> 6, l = tid & 63;
  const int m0 = blockIdx.y*128, n0 = blockIdx.x*64;
  const int ar = tid >> 1, ac = (tid & 1)*32;
  const int br = tid >> 2, bc = (tid & 3)*16;
  f32x4 acc[2][4] = {};
  for (int k0 = 0; k0 < K; k0 += 64){
    { const bf16x8* src = (const bf16x8*)&A[(size_t)(m0+ar)*K + k0 + ac];
      *(bf16x8*)&as[ar][ac]    = src[0];
      *(bf16x8*)&as[ar][ac+8]  = src[1];
      *(bf16x8*)&as[ar][ac+16] = src[2];
      *(bf16x8*)&as[ar][ac+24] = src[3];
    }
    { int n = n0 + br;
      bf16x8 z; z = (bf16x8)(short)0;
      bf16x8 b0 = z, b1 = z;
      if (n < N){
        const bf16x8* s = (const bf16x8*)&Bt[(size_t)n*K + k0 + bc];
        b0 = s[0]; b1 = s[1];
      }
      *(bf16x8*)&bs[br][bc]   = b0;
      *(bf16x8*)&bs[br][bc+8] = b1;
    }
    __syncthreads();
    const int lr = l & 15, kb = (l >> 4)*8;
    #pragma unroll
    for (int kc2 = 0; kc2 < 2; ++kc2){
      bf16x8 af0 = *(const bf16x8*)&as[w*32 + lr][kc2*32 + kb];
      bf16x8 af1 = *(const bf16x8*)&as[w*32 + 16 + lr][kc2*32 + kb];
      #pragma unroll
      for (int nt = 0; nt < 4; ++nt){
        bf16x8 bfr = *(const bf16x8*)&bs[nt*16 + lr][kc2*32 + kb];
        acc[0][nt] = __builtin_amdgcn_mfma_f32_16x16x32_bf16(af0, bfr, acc[0][nt], 0, 0, 0);
        acc[1][nt] = __builtin_amdgcn_mfma_f32_16x16x32_bf16(af1, bfr, acc[1][nt], 0, 0, 0);
      }
    }
    __syncthreads();
  }
  const int lr = l & 15;
  #pragma unroll
  for (int mt = 0; mt < 2; ++mt){
    #pragma unroll
    for (int nt = 0; nt < 4; ++nt){
      int col = n0 + nt*16 + lr;
      if (col < N){
        #pragma unroll
        for (int r = 0; r < 4; ++r){
          int row = m0 + w*32 + mt*16 + (l >> 4)*4 + r;
          if (MODE == 0 || MODE == 2) Cf[(size_t)row*N + col] = acc[mt][nt][r];
          if (MODE == 1 || MODE == 2) Cb[(size_t)row*N + col] = f2bf(acc[mt][nt][r]);
        }
      }
    }
  }
}

// ---- dual GEMM: Cu = A@BuT^T, Cg = A@BgT^T (shared A), BM=128 BN=64 -------
__global__ void __launch_bounds__(256) k_gemm_up(const unsigned short* __restrict__ A,
                                                 const unsigned short* __restrict__ But,
                                                 const unsigned short* __restrict__ Bgt,
                                                 unsigned short* __restrict__ Cu,
                                                 unsigned short* __restrict__ Cg){
  __shared__ unsigned short as[128][72];
  __shared__ unsigned short bu[64][72];
  __shared__ unsigned short bg[64][72];
  const int tid = threadIdx.x;
  const int w = tid >> 6, l = tid & 63;
  const int m0 = blockIdx.y*128, n0 = blockIdx.x*64;
  const int ar = tid >> 1, ac = (tid & 1)*32;
  const int br = tid >> 2, bc = (tid & 3)*16;
  f32x4 accu[2][4] = {}; f32x4 accg[2][4] = {};
  for (int k0 = 0; k0 < DD; k0 += 64){
    { const bf16x8* src = (const bf16x8*)&A[(size_t)(m0+ar)*DD + k0 + ac];
      *(bf16x8*)&as[ar][ac]    = src[0];
      *(bf16x8*)&as[ar][ac+8]  = src[1];
      *(bf16x8*)&as[ar][ac+16] = src[2];
      *(bf16x8*)&as[ar][ac+24] = src[3];
    }
    { const bf16x8* s0 = (const bf16x8*)&But[(size_t)(n0+br)*DD + k0 + bc];
      *(bf16x8*)&bu[br][bc]   = s0[0];
      *(bf16x8*)&bu[br][bc+8] = s0[1];
      const bf16x8* s1 = (const bf16x8*)&Bgt[(size_t)(n0+br)*DD + k0 + bc];
      *(bf16x8*)&bg[br][bc]   = s1[0];
      *(bf16x8*)&bg[br][bc+8] = s1[1];
    }
    __syncthreads();
    const int lr = l & 15, kb = (l >> 4)*8;
    #pragma unroll
    for (int kc2 = 0; kc2 < 2; ++kc2){
      bf16x8 af0 = *(const bf16x8*)&as[w*32 + lr][kc2*32 + kb];
      bf16x8 af1 = *(const bf16x8*)&as[w*32 + 16 + lr][kc2*32 + kb];
      #pragma unroll
      for (int nt = 0; nt < 4; ++nt){
        bf16x8 b0 = *(const bf16x8*)&bu[nt*16 + lr][kc2*32 + kb];
        accu[0][nt] = __builtin_amdgcn_mfma_f32_16x16x32_bf16(af0, b0, accu[0][nt], 0, 0, 0);
        accu[1][nt] = __builtin_amdgcn_mfma_f32_16x16x32_bf16(af1, b0, accu[1][nt], 0, 0, 0);
        bf16x8 b1 = *(const bf16x8*)&bg[nt*16 + lr][kc2*32 + kb];
        accg[0][nt] = __builtin_amdgcn_mfma_f32_16x16x32_bf16(af0, b1, accg[0][nt], 0, 0, 0);
        accg[1][nt] = __builtin_amdgcn_mfma_f32_16x16x32_bf16(af1, b1, accg[1][nt], 0, 0, 0);
      }
    }
    __syncthreads();
  }
  const int lr = l & 15;
  #pragma unroll
  for (int mt = 0; mt < 2; ++mt){
    #pragma unroll
    for (int nt = 0; nt < 4; ++nt){
      int col = n0 + nt*16 + lr;
      #pragma unroll
      for (int r = 0; r < 4; ++r){
        int row = m0 + w*32 + mt*16 + (l >> 4)*4 + r;
        Cu[(size_t)row*DIM + col] = f2bf(accu[mt][nt][r]);
        Cg[(size_t)row*DIM + col] = f2bf(accg[mt][nt][r]);
      }
    }
  }
}

// ---- Wout GEMM 64x64: fused comb (A = p0+p1) + resid --
__global__ void __launch_bounds__(256) k_gemm_wout(const float* __restrict__ p0,
                                                   const float* __restrict__ p1,
                                                   const unsigned short* __restrict__ Bt,
                                                   const float* __restrict__ y,
                                                   float* __restrict__ x){
  __shared__ unsigned short as[64][72];
  __shared__ unsigned short bs[64][72];
  const int tid = threadIdx.x;
  const int w = tid >> 6, l = tid & 63;
  const int m0 = blockIdx.y*64, n0 = blockIdx.x*64;
  const int ar = tid >> 2, ac = (tid & 3)*16;
  f32x4 acc[4] = {};
  for (int k0 = 0; k0 < DD; k0 += 64){
    #pragma unroll
    for (int j = 0; j < 4; ++j){
      size_t off = (size_t)(m0+ar)*DD + k0 + ac + j*4;
      float4 a = *(const float4*)&p0[off];
      float4 b = *(const float4*)&p1[off];
      a.x += b.x; a.y += b.y; a.z += b.z; a.w += b.w;
      ushort4 u = make_ushort4(f2bf(a.x), f2bf(a.y), f2bf(a.z), f2bf(a.w));
      *(ushort4*)&as[ar][ac + j*4] = u;
    }
    { const bf16x8* src = (const bf16x8*)&Bt[(size_t)(n0+ar)*DD + k0 + ac];
      *(bf16x8*)&bs[ar][ac]   = src[0];
      *(bf16x8*)&bs[ar][ac+8] = src[1];
    }
    __syncthreads();
    const int mr = w*16 + (l & 15);
    const int kb = (l >> 4)*8;
    #pragma unroll
    for (int kc2 = 0; kc2 < 2; ++kc2){
      bf16x8 af = *(const bf16x8*)&as[mr][kc2*32 + kb];
      #pragma unroll
      for (int nt = 0; nt < 4; ++nt){
        bf16x8 bfr = *(const bf16x8*)&bs[nt*16 + (l & 15)][kc2*32 + kb];
        acc[nt] = __builtin_amdgcn_mfma_f32_16x16x32_bf16(af, bfr, acc[nt], 0, 0, 0);
      }
    }
    __syncthreads();
  }
  #pragma unroll
  for (int nt = 0; nt < 4; ++nt){
    int col = n0 + nt*16 + (l & 15);
    #pragma unroll
    for (int r = 0; r < 4; ++r){
      int row = m0 + w*16 + (l >> 4)*4 + r;
      size_t off = (size_t)row*DD + col;
      x[off] = x[off] + y[off] + acc[nt][r];
    }
  }
}

// ------------ causal depthwise conv + silu gating, bf16 in/out ------------
__global__ void k_conv(const unsigned short* __restrict__ u,
                       const unsigned short* __restrict__ g,
                       const float* __restrict__ cw, const float* __restrict__ cb,
                       unsigned short* __restrict__ hh){
  int i8 = blockIdx.x*256 + threadIdx.x;
  int cg = i8 & 63;
  int bt = i8 >> 6;
  int t  = bt & (TT-1);
  int c0 = cg*8;
  float acc[8];
  { float4 b0 = *(const float4*)&cb[c0];
    float4 b1 = *(const float4*)&cb[c0+4];
    acc[0]=b0.x; acc[1]=b0.y; acc[2]=b0.z; acc[3]=b0.w;
    acc[4]=b1.x; acc[5]=b1.y; acc[6]=b1.z; acc[7]=b1.w; }
  float wts[8][4];
  #pragma unroll
  for (int i = 0; i < 8; ++i) *(float4*)&wts[i][0] = *(const float4*)&cw[(c0+i)*KW];
  #pragma unroll
  for (int j = 0; j < KW; ++j){
    int dt_ = j - (KW-1);
    if (t + dt_ >= 0){
      bf16x8 uv = *(const bf16x8*)&u[(size_t)(bt + dt_)*DIM + c0];
      #pragma unroll
      for (int i = 0; i < 8; ++i)
        acc[i] = fmaf(bf2f((unsigned short)uv[i]), wts[i][j], acc[i]);
    }
  }
  bf16x8 gv = *(const bf16x8*)&g[(size_t)bt*DIM + c0];
  bf16x8 o;
  #pragma unroll
  for (int i = 0; i < 8; ++i){
    float h = siluf(acc[i]);
    o[i] = (short)f2bf(siluf(bf2f((unsigned short)gv[i])) * h);
  }
  *(bf16x8*)&hh[(size_t)bt*DIM + c0] = o;
}

// ---- fused: proj + scal + rk-normalize (rk f32) ----
__global__ void __launch_bounds__(256) k_fused(const float* __restrict__ y,
    const float* __restrict__ Wg, const float* __restrict__ Wb,
    const float* __restrict__ Wa, const float* __restrict__ Wbl,
    const float* __restrict__ A_log, const float* __restrict__ dtb,
    float* __restrict__ rkb, float* __restrict__ scal){
  __shared__ float s_y[4][260];
  __shared__ float s_p[4][32];
  const int wv = threadIdx.x >> 6, l = threadIdx.x & 63;
  const int row = blockIdx.x*4 + wv;

  float4 yv = *(const float4*)&y[(size_t)row*DD + l*4];
  *(float4*)&s_y[wv][l*4] = yv;

  float ss = yv.x*yv.x + yv.y*yv.y + yv.z*yv.z + yv.w*yv.w;
  ss = xor1_add(ss); ss = xor2_add(ss);
  ss = ror4_add(ss); ss = ror8_add(ss);
  float inv = 1.f / fmaxf(sqrtf(ss), 1e-12f);
  float4 rv; rv.x = yv.x*inv; rv.y = yv.y*inv; rv.z = yv.z*inv; rv.w = yv.w*inv;
  *(float4*)&rkb[(size_t)row*DD + l*4] = rv;

  __syncthreads();

  const int j = (l < 28) ? l : 27;
  const float* wp; int stride;
  if (j < 4){ wp = Wg + j; stride = HH; }
  else if (j < 12){ int m=(j-4)>>2, h=(j-4)&3; wp = Wb + (size_t)m*DD*HH + h; stride = HH; }
  else if (j < 20){ int m=(j-12)>>2, h=(j-12)&3; wp = Wa + (size_t)m*DD*HH + h; stride = HH; }
  else { wp = Wbl + (j-20); stride = HH*MM; }
  float a0=0.f,a1=0.f,a2=0.f,a3=0.f;
  #pragma unroll 4
  for (int k = 0; k < DD; k += 4){
    a0 = fmaf(s_y[wv][k+0], wp[(k+0)*stride], a0);
    a1 = fmaf(s_y[wv][k+1], wp[(k+1)*stride], a1);
    a2 = fmaf(s_y[wv][k+2], wp[(k+2)*stride], a2);
    a3 = fmaf(s_y[wv][k+3], wp[(k+3)*stride], a3);
  }
  if (l < 28) s_p[wv][l] = (a0+a1)+(a2+a3);

  __syncthreads();

  if (l < 8){
    int m = l >> 2, h = l & 3;
    float gs  = sigf(s_p[wv][h]);
    float btv = sigf(s_p[wv][4 + m*4 + h]);
    float sp  = s_p[wv][12 + m*4 + h] + dtb[m*HH + h];
    sp = (sp > 15.f) ? sp : log1pf(__expf(sp));
    float dc  = __expf(-__expf(A_log[m*HH + h]) * sp);
    float l0 = s_p[wv][20 + h*2], l1 = s_p[wv][20 + h*2 + 1];
    float mx = fmaxf(l0, l1);
    float e0 = __expf(l0-mx), e1 = __expf(l1-mx);
    float bl = (m ? e1 : e0) / (e0 + e1);
    float4 o; o.x = dc; o.y = btv; o.z = bl*gs; o.w = 0.f;
    *(float4*)&scal[((size_t)row*MM + m)*(HH*4) + h*4] = o;
  }
}

// ---- ip precompute: ip1(t)=<rk(t-1),rk(t)>, ip2(t)=<rk(t-2),rk(t)> per (row,h)
// layout: ipg[h][row][2] with row stride RP.
__global__ void __launch_bounds__(256) k_ip(const float* __restrict__ rkb,
                                            float* __restrict__ ipg){
  const int wv = threadIdx.x >> 6, l = threadIdx.x & 63;
  const int row = blockIdx.x*4 + wv;
  const int t = row & (TT-1);
  float4 a = *(const float4*)&rkb[(size_t)row*DD + l*4];
  float4 b1 = make_float4(0.f,0.f,0.f,0.f), b2 = b1;
  if (t >= 1) b1 = *(const float4*)&rkb[(size_t)(row-1)*DD + l*4];
  if (t >= 2) b2 = *(const float4*)&rkb[(size_t)(row-2)*DD + l*4];
  float p1 = a.x*b1.x; p1 = fmaf(a.y,b1.y,p1); p1 = fmaf(a.z,b1.z,p1); p1 = fmaf(a.w,b1.w,p1);
  float p2 = a.x*b2.x; p2 = fmaf(a.y,b2.y,p2); p2 = fmaf(a.z,b2.z,p2); p2 = fmaf(a.w,b2.w,p2);
  p1 = xor1_add(p1); p1 = xor2_add(p1); p1 = ror4_add(p1); p1 = ror8_add(p1);
  p2 = xor1_add(p2); p2 = xor2_add(p2); p2 = ror4_add(p2); p2 = ror8_add(p2);
  if ((l & 15) == 0){
    int h = l >> 4;
    float2 o; o.x = p1; o.y = p2;
    *(float2*)&ipg[((size_t)h*RP + row)*2] = o;
  }
}

// ---------------- scan: chained-scalar formulation ----------
// rr(t) = dc*u(t) + err(t)*ip1(t);  u(t) = dc(t-1)*w(t) + err(t-1)*ip2(t);
// w(t) = <S(t-2), rk(t)> (fresh cross-lane dot, 1 step of slack).
// Chain per step: err(2 ops) -> rr(1 fma). Boot: first 2 steps/chunk direct.

#define WIRE(d0,d1,d2,d3, src) \
  float d0,d1,d2,d3; \
  if (ROT == 0){ d0=src.x; d1=src.y; d2=src.z; d3=src.w; } \
  else { d0=-src.y; d1=src.x; d2=-src.w; d3=src.z; }

// boot step: direct dot (R13 style) + exports err/dc + ip prefetch
#define BSTEP(T_, WK, RK, PF, VB, SB, IPB, ERRO, DCO) { \
  const float dc = SB.x, btv = SB.y, blg = SB.z; \
  const float v = VB; \
  { const int tn_ = (T_)+2; \
    PF = *(const float4*)&s_rk[p][tn_][dbase]; \
    VB = bf2f(s_v[p][tn_][vidx]); \
    SB = *(const float4*)&s_sc[p][tn_][0]; \
    IPB = *(const float2*)&s_ip[p][tn_][0]; } \
  const float err = (v - dc*rrc)*btv; \
  float rr0=0.f, rr1=0.f; \
  { WIRE(w0,w1,w2,w3, WK) WIRE(c0,c1,c2,c3, RK) \
    S[0] = fmaf(S[0], dc, w0*err); rr0 = fmaf(S[0], c0, rr0); \
    S[1] = fmaf(S[1], dc, w1*err); rr1 = fmaf(S[1], c1, rr1); \
    S[2] = fmaf(S[2], dc, w2*err); rr0 = fmaf(S[2], c2, rr0); \
    S[3] = fmaf(S[3], dc, w3*err); rr1 = fmaf(S[3], c3, rr1); } \
  float rr = rr0 + rr1; \
  rr = xor1_add(rr); rr = xor2_add(rr); rr = ror4_add(rr); rr = ror8_add(rr); \
  rrc = rr; \
  if (seg == 0) part[(size_t)(rowchunk + (T_))*DD + h*HDIM + kq4*4 + klocal] = blg*rr; \
  ERRO = err; DCO = dc; \
}

// fast step
#define FSTEP(T_, WK, RN, PF, VB, SB, IPB, SBo, IPBo) { \
  const float dc = SB.x, btv = SB.y, blg = SB.z; \
  const float ip1v = IPB.x; \
  const float v = VB; \
  const float dcN = SBo.x; \
  const float ip2N = IPBo.y; \
  /* pd for w(t+1) from old S and rk(t+1) */ \
  float wv1; \
  { WIRE(c0,c1,c2,c3, RN) \
    float q0 = S[0]*c0; q0 = fmaf(S[2], c2, q0); \
    float q1 = S[1]*c1; q1 = fmaf(S[3], c3, q1); \
    wv1 = q0 + q1; } \
  /* prefetch t+2 */ \
  { const int tn_ = ((T_)+2 < 64) ? (T_)+2 : 63; \
    PF = *(const float4*)&s_rk[p][tn_][dbase]; \
    VB = bf2f(s_v[p][tn_][vidx]); \
    SB = *(const float4*)&s_sc[p][tn_][0]; \
    IPB = *(const float2*)&s_ip[p][tn_][0]; } \
  /* scalar chain */ \
  const float err = (v - dc*rrc)*btv; \
  const float rr = fmaf(err, ip1v, du); \
  rrc = rr; \
  if (seg == 0) part[(size_t)(rowchunk + (T_))*DD + h*HDIM + kq4*4 + klocal] = blg*rr; \
  /* S update */ \
  { WIRE(w0,w1,w2,w3, WK) \
    S[0] = fmaf(S[0], dc, w0*err); \
    S[1] = fmaf(S[1], dc, w1*err); \
    S[2] = fmaf(S[2], dc, w2*err); \
    S[3] = fmaf(S[3], dc, w3*err); } \
  /* finish w(t+1) reduce; pipeline scalars */ \
  wv1 = xor1_add(wv1); wv1 = xor2_add(wv1); wv1 = ror4_add(wv1); wv1 = ror8_add(wv1); \
  const float u1 = fmaf(err, ip2N, dc*wv1); \
  du = dcN * u1; \
}

template<int ROT>
__device__ __forceinline__ void scan_body(int b, int h, int kq4, int l,
    const unsigned short* __restrict__ vals, const float* __restrict__ rkb,
    const float* __restrict__ scal, const float* __restrict__ ipg,
    float* __restrict__ part,
    float (*s_rk)[64][64], unsigned short (*s_v)[64][8], float (*s_sc)[64][4],
    float (*s_ip)[128][2])
{
  const int seg = l & 15, klocal = l >> 4;
  const int dbase = seg*4;
  const int vidx = (kq4 & 1)*4 + klocal;
  const int kq8 = kq4 >> 1;
  const int rowbase = b*TT;

  float S[4];
  #pragma unroll
  for (int j = 0; j < 4; ++j) S[j] = 0.f;
  const float4 Z = make_float4(0.f,0.f,0.f,0.f);
  float4 rb0 = Z, rb1 = Z, rb2 = Z, rb3 = Z;
  float vb0 = 0.f, vb1 = 0.f;
  float4 sb0 = Z, sb1 = Z;
  float2 ipb0 = make_float2(0.f,0.f), ipb1 = ipb0;
  float rrc = 0.f;
  float du = 0.f;

  auto stage = [&](int c, int pbuf){
    const int r0 = rowbase + c*64;
    #pragma unroll
    for (int i = 0; i < 16; ++i){
      const float* g = rkb + (size_t)(r0 + i*4 + (l>>4))*DD + h*HDIM + (l&15)*4;
      gl_lds16(g, &s_rk[pbuf][i*4][0]);
    }
    { const unsigned short* g = vals + ((size_t)(r0 + l)*MM + ROT)*DD + h*HDIM + kq8*8;
      gl_lds16(g, &s_v[pbuf][0][0]); }
    { const float* g = scal + ((size_t)(r0 + l)*MM + ROT)*(HH*4) + h*4;
      gl_lds16(g, &s_sc[pbuf][0][0]); }
    { const float* g = ipg + ((size_t)h*RP + r0)*2 + l*4;
      gl_lds16(g, &s_ip[pbuf][0][0]); }
  };

  stage(0, 0);
  for (int c = 0; c < TT/64; ++c){
    const int p = c & 1;
    __syncthreads();                 // vmcnt drain: chunk c staged
    if (c + 1 < TT/64) stage(c+1, p^1);
    rb0 = *(const float4*)&s_rk[p][0][dbase];
    rb1 = *(const float4*)&s_rk[p][1][dbase];
    vb0 = bf2f(s_v[p][0][vidx]); vb1 = bf2f(s_v[p][1][vidx]);
    sb0 = *(const float4*)&s_sc[p][0][0]; sb1 = *(const float4*)&s_sc[p][1][0];
    const int rowchunk = rowbase + c*64;

    float err0, dc0d, err1, dc1d;
    BSTEP(0, rb3, rb0, rb2, vb0, sb0, ipb0, err0, dc0d)   // pos0
    (void)err0; (void)dc0d;
    // pd for w(2) from S(0) and rk(2)=rb2
    float wv2;
    { WIRE(c0,c1,c2,c3, rb2)
      float q0 = S[0]*c0; q0 = fmaf(S[2], c2, q0);
      float q1 = S[1]*c1; q1 = fmaf(S[3], c3, q1);
      wv2 = q0 + q1;
      wv2 = xor1_add(wv2); wv2 = xor2_add(wv2); wv2 = ror4_add(wv2); wv2 = ror8_add(wv2); }
    BSTEP(1, rb0, rb1, rb3, vb1, sb1, ipb1, err1, dc1d)   // pos1
    { float u2 = fmaf(err1, ipb0.y, dc1d*wv2);            // ip2(2) = ipb0.y
      du = sb0.x * u2; }                                  // dc(2) = sb0.x
    FSTEP(2, rb1, rb3, rb0, vb0, sb0, ipb0, sb1, ipb1)    // pos2
    FSTEP(3, rb2, rb0, rb1, vb1, sb1, ipb1, sb0, ipb0)    // pos3
    for (int tt = 4; tt < 64; tt += 4){
      FSTEP(tt+0, rb3, rb1, rb2, vb0, sb0, ipb0, sb1, ipb1)
      FSTEP(tt+1, rb0, rb2, rb3, vb1, sb1, ipb1, sb0, ipb0)
      FSTEP(tt+2, rb1, rb3, rb0, vb0, sb0, ipb0, sb1, ipb1)
      FSTEP(tt+3, rb2, rb0, rb1, vb1, sb1, ipb1, sb0, ipb0)
    }
  }
}

__global__ void __launch_bounds__(64) k_scan(const unsigned short* __restrict__ vals,
                                             const float* __restrict__ rkb,
                                             const float* __restrict__ scal,
                                             const float* __restrict__ ipg,
                                             float* __restrict__ partials){
  __shared__ float s_rk[2][64][64];
  __shared__ unsigned short s_v[2][64][8];
  __shared__ float s_sc[2][64][4];
  __shared__ float s_ip[2][128][2];
  const int bi = blockIdx.x;      // (((b*HH)+h)*MM + m)*16 + kq4
  const int kq4 = bi & 15;
  const int m  = (bi >> 4) & 1;
  const int h  = (bi >> 5) & 3;
  const int b  = bi >> 7;
  float* part = partials + (size_t)m*(BB*TT*DD);
  if (m == 0) scan_body<0>(b, h, kq4, threadIdx.x, vals, rkb, scal, ipg, part, s_rk, s_v, s_sc, s_ip);
  else        scan_body<1>(b, h, kq4, threadIdx.x, vals, rkb, scal, ipg, part, s_rk, s_v, s_sc, s_ip);
}

extern "C" void kernel_launch(void* const* d_in, const int* in_sizes, int n_in,
                              void* d_out, int out_size, void* d_ws, size_t ws_size,
                              hipStream_t stream){
  const int*   ids   = (const int*)d_in[0];
  const float* emb   = (const float*)d_in[1];
  const float* normw = (const float*)d_in[2];
  const float* Wup   = (const float*)d_in[3];
  const float* Wgate = (const float*)d_in[4];
  const float* Wdown = (const float*)d_in[5];
  const float* convw = (const float*)d_in[6];
  const float* convb = (const float*)d_in[7];
  const float* Wv    = (const float*)d_in[8];
  const float* Wg    = (const float*)d_in[9];
  const float* Wb    = (const float*)d_in[10];
  const float* Wa    = (const float*)d_in[11];
  const float* A_log = (const float*)d_in[12];
  const float* dtb   = (const float*)d_in[13];
  const float* Wbl   = (const float*)d_in[14];
  const float* Wout  = (const float*)d_in[15];
  const float* fnw   = (const float*)d_in[16];
  float* out = (float*)d_out;

  const int ROWS = BB*TT;              // 4096
  const size_t MEG = 1u << 20;
  float* ws   = (float*)d_ws;
  float* x    = ws;                        // 1M f32
  unsigned short* nyb = (unsigned short*)(x + MEG);    // 1M bf16
  float* big1 = x + MEG + MEG/2;           // 2M floats
  float* big2 = big1 + 2*MEG;              // 2M f32: partials
  float* y    = big2 + 2*MEG;              // 1M f32
  float* rkb  = y    + MEG;                // 1M f32
  float* scal = rkb  + MEG;                // 128K f32
  float* ipg  = scal + (1u<<17);           // HH*RP*2 floats (~34K)
  unsigned short* wbf = (unsigned short*)(ipg + (size_t)HH*RP*2 + 256);

  unsigned short* ub  = (unsigned short*)big1;
  unsigned short* gb  = (unsigned short*)(big1 + MEG);
  unsigned short* valsb = ub;

  { int total = 2*LWB + VV*DD;
    k_cvt<<<(total + 255)/256, 256, 0, stream>>>(Wup, Wgate, Wdown, Wv, Wout, emb, wbf); }

  k_embed_norm<<<ROWS/4, 256, 0, stream>>>(ids, emb, normw, x, nyb);

  for (int l = 0; l < LL; ++l){
    unsigned short* wl = wbf + (size_t)l*LWB;
    unsigned short* upT   = wl;
    unsigned short* gateT = wl + 131072;
    unsigned short* downT = wl + 262144;
    unsigned short* wvT   = wl + 393216;
    unsigned short* woutT = wl + 524288;

    if (l > 0) k_rmsnorm<<<ROWS/4, 256, 0, stream>>>(x, normw + l*DD, nyb);
    k_gemm_up<<<dim3(DIM/64, ROWS/128), 256, 0, stream>>>(nyb, upT, gateT, ub, gb);
    k_conv<<<(ROWS*DIM/8)/256, 256, 0, stream>>>(ub, gb, convw + l*DIM*KW, convb + l*DIM, gb);
    k_gemm64<2><<<dim3(DD/64, ROWS/64), 256, 0, stream>>>(gb, downT, y, nyb, DD, DIM);
    k_gemm128<1><<<dim3(DIM/64, ROWS/128), 256, 0, stream>>>(nyb, wvT, nullptr, valsb, DIM, DD);
    k_fused<<<ROWS/4, 256, 0, stream>>>(y, Wg + l*DD*HH, Wb + (size_t)l*MM*DD*HH,
                                        Wa + (size_t)l*MM*DD*HH, Wbl + l*DD*HH*MM,
                                        A_log + l*MM*HH, dtb + l*MM*HH, rkb, scal);
    k_ip<<<ROWS/4, 256, 0, stream>>>(rkb, ipg);
    k_scan<<<BB*HH*MM*16, 64, 0, stream>>>(valsb, rkb, scal, ipg, big2);
    k_gemm_wout<<<dim3(DD/64, ROWS/64), 256, 0, stream>>>(big2, big2 + MEG, woutT, y, x);
  }

  unsigned short* embT = wbf + 2*LWB;   // [272][256] bf16
  k_rmsnorm<<<ROWS/4, 256, 0, stream>>>(x, fnw, nyb);
  k_gemm64<0><<<dim3((VV+63)/64, ROWS/64), 256, 0, stream>>>(nyb, embT, out, nullptr, VV, DD);
}

// Round 18
// 284.944 us; speedup vs baseline: 1.0417x; 1.0417x over previous
//
#include <hip/hip_runtime.h>
#include <math.h>

#define BB 8
#define TT 512
#define DD 256
#define DIM 512
#define KW 4
#define MM 2
#define HH 4
#define HDIM 64
#define LL 2
#define VV 272

typedef __attribute__((ext_vector_type(8))) short bf16x8;
typedef __attribute__((ext_vector_type(4))) float f32x4;

__device__ __forceinline__ float sigf(float x){ return 1.f/(1.f+__expf(-x)); }
__device__ __forceinline__ float siluf(float x){ return x/(1.f+__expf(-x)); }

__device__ __forceinline__ unsigned short f2bf(float f){
  unsigned int u = __float_as_uint(f);
  unsigned int r = (u + 0x7FFFu + ((u >> 16) & 1u)) >> 16;
  return (unsigned short)r;
}
__device__ __forceinline__ float bf2f(unsigned short s){
  return __uint_as_float(((unsigned int)s) << 16);
}

// DPP reduces (no DS ops)
__device__ __forceinline__ float xor1_add(float x){
  int y = __builtin_amdgcn_update_dpp(0, __float_as_int(x), 0xB1, 0xF, 0xF, true);
  return x + __int_as_float(y);
}
__device__ __forceinline__ float xor2_add(float x){
  int y = __builtin_amdgcn_update_dpp(0, __float_as_int(x), 0x4E, 0xF, 0xF, true);
  return x + __int_as_float(y);
}
__device__ __forceinline__ float ror4_add(float x){
  int y = __builtin_amdgcn_update_dpp(0, __float_as_int(x), 0x124, 0xF, 0xF, true);
  return x + __int_as_float(y);
}
__device__ __forceinline__ float ror8_add(float x){
  int y = __builtin_amdgcn_update_dpp(0, __float_as_int(x), 0x128, 0xF, 0xF, true);
  return x + __int_as_float(y);
}

// async global->LDS, 16B per lane. LDS dest is wave-uniform base + lane*16.
__device__ __forceinline__ void gl_lds16(const void* g, void* l){
  __builtin_amdgcn_global_load_lds(
      (const __attribute__((address_space(1))) unsigned int*)g,
      (__attribute__((address_space(3))) unsigned int*)l,
      16, 0, 0);
}

// ---------------- weight convert + transpose to bf16 [N][K] ----------------
// Folds normw (layer 1 only) into upT/gateT, and fnw into embT.
#define LWB 589824
__global__ void k_cvt(const float* __restrict__ Wup, const float* __restrict__ Wgate,
                      const float* __restrict__ Wdown, const float* __restrict__ Wv,
                      const float* __restrict__ Wout, const float* __restrict__ emb,
                      const float* __restrict__ normw, const float* __restrict__ fnw,
                      unsigned short* __restrict__ wbf){
  int idx = blockIdx.x*256 + threadIdx.x;
  if (idx >= 2*LWB + VV*DD) return;
  float v;
  if (idx < 2*LWB){
    int l = (idx >= LWB) ? 1 : 0;
    int local = idx - l*LWB;
    if (local < 131072){ int n = local>>8, k = local&255;
      v = Wup[(size_t)l*131072 + k*DIM + n];
      if (l == 1) v *= normw[DD + k]; }
    else if (local < 262144){ local -= 131072; int n = local>>8, k = local&255;
      v = Wgate[(size_t)l*131072 + k*DIM + n];
      if (l == 1) v *= normw[DD + k]; }
    else if (local < 393216){ local -= 262144; int n = local>>9, k = local&511;
      v = Wdown[(size_t)l*131072 + k*DD + n]; }
    else if (local < 524288){ local -= 393216; int n = local>>8, k = local&255;
      v = Wv[(size_t)l*131072 + k*DIM + n]; }
    else { local -= 524288; int n = local>>8, k = local&255;
      v = Wout[(size_t)l*65536 + k*DD + n]; }
  } else {
    int k = (idx - 2*LWB) & 255;
    v = emb[idx - 2*LWB] * fnw[k];
  }
  wbf[idx] = f2bf(v);
}

// ------- fused embedding gather + rmsnorm (layer 0) ---
__global__ void __launch_bounds__(256) k_embed_norm(const int* __restrict__ ids,
                                                    const float* __restrict__ emb,
                                                    const float* __restrict__ w,
                                                    float* __restrict__ x,
                                                    unsigned short* __restrict__ out){
  const int wv = threadIdx.x >> 6, l = threadIdx.x & 63;
  const int row = blockIdx.x*4 + wv;
  float4 v = *(const float4*)&emb[(size_t)ids[row]*DD + l*4];
  *(float4*)&x[(size_t)row*DD + l*4] = v;
  float ss = v.x*v.x + v.y*v.y + v.z*v.z + v.w*v.w;
  #pragma unroll
  for (int o = 32; o > 0; o >>= 1) ss += __shfl_xor(ss, o, 64);
  float sc = rsqrtf(ss*(1.f/DD) + 1e-6f);
  float4 wvv = *(const float4*)&w[l*4];
  ushort4 r;
  r.x = f2bf(v.x*sc*wvv.x); r.y = f2bf(v.y*sc*wvv.y);
  r.z = f2bf(v.z*sc*wvv.z); r.w = f2bf(v.w*sc*wvv.w);
  *(ushort4*)&out[(size_t)row*DD + l*4] = r;
}

// -------- bf16 GEMM 64x64 tile (4 waves) --------
template<int MODE>
__global__ void __launch_bounds__(256) k_gemm64(const unsigned short* __restrict__ A,
                                                const unsigned short* __restrict__ Bt,
                                                float* __restrict__ Cf,
                                                unsigned short* __restrict__ Cb,
                                                int N, int K){
  __shared__ unsigned short as[64][72];
  __shared__ unsigned short bs[64][72];
  const int tid = threadIdx.x;
  const int w = tid >> 6, l = tid & 63;
  const int m0 = blockIdx.y*64, n0 = blockIdx.x*64;
  const int ar = tid >> 2, ac = (tid & 3)*16;
  f32x4 acc[4] = {};
  for (int k0 = 0; k0 < K; k0 += 64){
    { const bf16x8* src = (const bf16x8*)&A[(size_t)(m0+ar)*K + k0 + ac];
      *(bf16x8*)&as[ar][ac]   = src[0];
      *(bf16x8*)&as[ar][ac+8] = src[1];
    }
    { int n = n0 + ar;
      bf16x8 z; z = (bf16x8)(short)0;
      bf16x8 b0 = z, b1 = z;
      if (n < N){
        const bf16x8* src = (const bf16x8*)&Bt[(size_t)n*K + k0 + ac];
        b0 = src[0]; b1 = src[1];
      }
      *(bf16x8*)&bs[ar][ac]   = b0;
      *(bf16x8*)&bs[ar][ac+8] = b1;
    }
    __syncthreads();
    const int mr = w*16 + (l & 15);
    const int kb = (l >> 4)*8;
    #pragma unroll
    for (int kc2 = 0; kc2 < 2; ++kc2){
      bf16x8 af = *(const bf16x8*)&as[mr][kc2*32 + kb];
      #pragma unroll
      for (int nt = 0; nt < 4; ++nt){
        bf16x8 bfr = *(const bf16x8*)&bs[nt*16 + (l & 15)][kc2*32 + kb];
        acc[nt] = __builtin_amdgcn_mfma_f32_16x16x32_bf16(af, bfr, acc[nt], 0, 0, 0);
      }
    }
    __syncthreads();
  }
  #pragma unroll
  for (int nt = 0; nt < 4; ++nt){
    int col = n0 + nt*16 + (l & 15);
    if (col < N){
      #pragma unroll
      for (int r = 0; r < 4; ++r){
        int row = m0 + w*16 + (l >> 4)*4 + r;
        if (MODE == 0 || MODE == 2) Cf[(size_t)row*N + col] = acc[nt][r];
        if (MODE == 1 || MODE == 2) Cb[(size_t)row*N + col] = f2bf(acc[nt][r]);
      }
    }
  }
}

// -------- logits GEMM: A = x (f32) normalized on the fly via rowssq ---------
// fnw already folded into Bt (embT). C f32.
__global__ void __launch_bounds__(256) k_gemmlogit(const float* __restrict__ X,
                                                   const float* __restrict__ pssq,
                                                   const unsigned short* __restrict__ Bt,
                                                   float* __restrict__ Cf,
                                                   int N, int K){
  __shared__ unsigned short as[64][72];
  __shared__ unsigned short bs[64][72];
  const int tid = threadIdx.x;
  const int w = tid >> 6, l = tid & 63;
  const int m0 = blockIdx.y*64, n0 = blockIdx.x*64;
  const int ar = tid >> 2, ac = (tid & 3)*16;
  const int arow = m0 + ar;
  const int ROWS = BB*TT;
  float ssq = pssq[arow] + pssq[ROWS + arow] + pssq[2*ROWS + arow] + pssq[3*ROWS + arow];
  const float sc = rsqrtf(ssq*(1.f/DD) + 1e-6f);
  f32x4 acc[4] = {};
  for (int k0 = 0; k0 < K; k0 += 64){
    { const float* src = &X[(size_t)arow*K + k0 + ac];
      #pragma unroll
      for (int j = 0; j < 4; ++j){
        float4 a = *(const float4*)&src[j*4];
        ushort4 u = make_ushort4(f2bf(a.x*sc), f2bf(a.y*sc), f2bf(a.z*sc), f2bf(a.w*sc));
        *(ushort4*)&as[ar][ac + j*4] = u;
      }
    }
    { int n = n0 + ar;
      bf16x8 z; z = (bf16x8)(short)0;
      bf16x8 b0 = z, b1 = z;
      if (n < N){
        const bf16x8* src = (const bf16x8*)&Bt[(size_t)n*K + k0 + ac];
        b0 = src[0]; b1 = src[1];
      }
      *(bf16x8*)&bs[ar][ac]   = b0;
      *(bf16x8*)&bs[ar][ac+8] = b1;
    }
    __syncthreads();
    const int mr = w*16 + (l & 15);
    const int kb = (l >> 4)*8;
    #pragma unroll
    for (int kc2 = 0; kc2 < 2; ++kc2){
      bf16x8 af = *(const bf16x8*)&as[mr][kc2*32 + kb];
      #pragma unroll
      for (int nt = 0; nt < 4; ++nt){
        bf16x8 bfr = *(const bf16x8*)&bs[nt*16 + (l & 15)][kc2*32 + kb];
        acc[nt] = __builtin_amdgcn_mfma_f32_16x16x32_bf16(af, bfr, acc[nt], 0, 0, 0);
      }
    }
    __syncthreads();
  }
  #pragma unroll
  for (int nt = 0; nt < 4; ++nt){
    int col = n0 + nt*16 + (l & 15);
    if (col < N){
      #pragma unroll
      for (int r = 0; r < 4; ++r){
        int row = m0 + w*16 + (l >> 4)*4 + r;
        Cf[(size_t)row*N + col] = acc[nt][r];
      }
    }
  }
}

// -------- bf16 GEMM 128x64 tile (4 waves) --------
template<int MODE>
__global__ void __launch_bounds__(256) k_gemm128(const unsigned short* __restrict__ A,
                                                 const unsigned short* __restrict__ Bt,
                                                 float* __restrict__ Cf,
                                                 unsigned short* __restrict__ Cb,
                                                 int N, int K){
  __shared__ unsigned short as[128][72];
  __shared__ unsigned short bs[64][72];
  const int tid = threadIdx.x;
  const int w = tid >> 6, l = tid & 63;
  const int m0 = blockIdx.y*128, n0 = blockIdx.x*64;
  const int ar = tid >> 1, ac = (tid & 1)*32;
  const int br = tid >> 2, bc = (tid & 3)*16;
  f32x4 acc[2][4] = {};
  for (int k0 = 0; k0 < K; k0 += 64){
    { const bf16x8* src = (const bf16x8*)&A[(size_t)(m0+ar)*K + k0 + ac];
      *(bf16x8*)&as[ar][ac]    = src[0];
      *(bf16x8*)&as[ar][ac+8]  = src[1];
      *(bf16x8*)&as[ar][ac+16] = src[2];
      *(bf16x8*)&as[ar][ac+24] = src[3];
    }
    { int n = n0 + br;
      bf16x8 z; z = (bf16x8)(short)0;
      bf16x8 b0 = z, b1 = z;
      if (n < N){
        const bf16x8* s = (const bf16x8*)&Bt[(size_t)n*K + k0 + bc];
        b0 = s[0]; b1 = s[1];
      }
      *(bf16x8*)&bs[br][bc]   = b0;
      *(bf16x8*)&bs[br][bc+8] = b1;
    }
    __syncthreads();
    const int lr = l & 15, kb = (l >> 4)*8;
    #pragma unroll
    for (int kc2 = 0; kc2 < 2; ++kc2){
      bf16x8 af0 = *(const bf16x8*)&as[w*32 + lr][kc2*32 + kb];
      bf16x8 af1 = *(const bf16x8*)&as[w*32 + 16 + lr][kc2*32 + kb];
      #pragma unroll
      for (int nt = 0; nt < 4; ++nt){
        bf16x8 bfr = *(const bf16x8*)&bs[nt*16 + lr][kc2*32 + kb];
        acc[0][nt] = __builtin_amdgcn_mfma_f32_16x16x32_bf16(af0, bfr, acc[0][nt], 0, 0, 0);
        acc[1][nt] = __builtin_amdgcn_mfma_f32_16x16x32_bf16(af1, bfr, acc[1][nt], 0, 0, 0);
      }
    }
    __syncthreads();
  }
  const int lr = l & 15;
  #pragma unroll
  for (int mt = 0; mt < 2; ++mt){
    #pragma unroll
    for (int nt = 0; nt < 4; ++nt){
      int col = n0 + nt*16 + lr;
      if (col < N){
        #pragma unroll
        for (int r = 0; r < 4; ++r){
          int row = m0 + w*32 + mt*16 + (l >> 4)*4 + r;
          if (MODE == 0 || MODE == 2) Cf[(size_t)row*N + col] = acc[mt][nt][r];
          if (MODE == 1 || MODE == 2) Cb[(size_t)row*N + col] = f2bf(acc[mt][nt][r]);
        }
      }
    }
  }
}

// ---- dual GEMM layer0: Cu = A@BuT^T, Cg = A@BgT^T (A bf16, pre-normalized) --
__global__ void __launch_bounds__(256) k_gemm_up(const unsigned short* __restrict__ A,
                                                 const unsigned short* __restrict__ But,
                                                 const unsigned short* __restrict__ Bgt,
                                                 unsigned short* __restrict__ Cu,
                                                 unsigned short* __restrict__ Cg){
  __shared__ unsigned short as[128][72];
  __shared__ unsigned short bu[64][72];
  __shared__ unsigned short bg[64][72];
  const int tid = threadIdx.x;
  const int w = tid >> 6, l = tid & 63;
  const int m0 = blockIdx.y*128, n0 = blockIdx.x*64;
  const int ar = tid >> 1, ac = (tid & 1)*32;
  const int br = tid >> 2, bc = (tid & 3)*16;
  f32x4 accu[2][4] = {}; f32x4 accg[2][4] = {};
  for (int k0 = 0; k0 < DD; k0 += 64){
    { const bf16x8* src = (const bf16x8*)&A[(size_t)(m0+ar)*DD + k0 + ac];
      *(bf16x8*)&as[ar][ac]    = src[0];
      *(bf16x8*)&as[ar][ac+8]  = src[1];
      *(bf16x8*)&as[ar][ac+16] = src[2];
      *(bf16x8*)&as[ar][ac+24] = src[3];
    }
    { const bf16x8* s0 = (const bf16x8*)&But[(size_t)(n0+br)*DD + k0 + bc];
      *(bf16x8*)&bu[br][bc]   = s0[0];
      *(bf16x8*)&bu[br][bc+8] = s0[1];
      const bf16x8* s1 = (const bf16x8*)&Bgt[(size_t)(n0+br)*DD + k0 + bc];
      *(bf16x8*)&bg[br][bc]   = s1[0];
      *(bf16x8*)&bg[br][bc+8] = s1[1];
    }
    __syncthreads();
    const int lr = l & 15, kb = (l >> 4)*8;
    #pragma unroll
    for (int kc2 = 0; kc2 < 2; ++kc2){
      bf16x8 af0 = *(const bf16x8*)&as[w*32 + lr][kc2*32 + kb];
      bf16x8 af1 = *(const bf16x8*)&as[w*32 + 16 + lr][kc2*32 + kb];
      #pragma unroll
      for (int nt = 0; nt < 4; ++nt){
        bf16x8 b0 = *(const bf16x8*)&bu[nt*16 + lr][kc2*32 + kb];
        accu[0][nt] = __builtin_amdgcn_mfma_f32_16x16x32_bf16(af0, b0, accu[0][nt], 0, 0, 0);
        accu[1][nt] = __builtin_amdgcn_mfma_f32_16x16x32_bf16(af1, b0, accu[1][nt], 0, 0, 0);
        bf16x8 b1 = *(const bf16x8*)&bg[nt*16 + lr][kc2*32 + kb];
        accg[0][nt] = __builtin_amdgcn_mfma_f32_16x16x32_bf16(af0, b1, accg[0][nt], 0, 0, 0);
        accg[1][nt] = __builtin_amdgcn_mfma_f32_16x16x32_bf16(af1, b1, accg[1][nt], 0, 0, 0);
      }
    }
    __syncthreads();
  }
  const int lr = l & 15;
  #pragma unroll
  for (int mt = 0; mt < 2; ++mt){
    #pragma unroll
    for (int nt = 0; nt < 4; ++nt){
      int col = n0 + nt*16 + lr;
      #pragma unroll
      for (int r = 0; r < 4; ++r){
        int row = m0 + w*32 + mt*16 + (l >> 4)*4 + r;
        Cu[(size_t)row*DIM + col] = f2bf(accu[mt][nt][r]);
        Cg[(size_t)row*DIM + col] = f2bf(accg[mt][nt][r]);
      }
    }
  }
}

// ---- dual GEMM layer1: A = x (f32), normalized on the fly via rowssq -------
// normw[1] folded into But/Bgt.
__global__ void __launch_bounds__(256) k_gemm_up2(const float* __restrict__ X,
                                                  const float* __restrict__ pssq,
                                                  const unsigned short* __restrict__ But,
                                                  const unsigned short* __restrict__ Bgt,
                                                  unsigned short* __restrict__ Cu,
                                                  unsigned short* __restrict__ Cg){
  __shared__ unsigned short as[128][72];
  __shared__ unsigned short bu[64][72];
  __shared__ unsigned short bg[64][72];
  const int tid = threadIdx.x;
  const int w = tid >> 6, l = tid & 63;
  const int m0 = blockIdx.y*128, n0 = blockIdx.x*64;
  const int ar = tid >> 1, ac = (tid & 1)*32;
  const int br = tid >> 2, bc = (tid & 3)*16;
  const int arow = m0 + ar;
  const int ROWS = BB*TT;
  float ssq = pssq[arow] + pssq[ROWS + arow] + pssq[2*ROWS + arow] + pssq[3*ROWS + arow];
  const float sc = rsqrtf(ssq*(1.f/DD) + 1e-6f);
  f32x4 accu[2][4] = {}; f32x4 accg[2][4] = {};
  for (int k0 = 0; k0 < DD; k0 += 64){
    { const float* src = &X[(size_t)arow*DD + k0 + ac];
      #pragma unroll
      for (int j = 0; j < 8; ++j){
        float4 a = *(const float4*)&src[j*4];
        ushort4 u = make_ushort4(f2bf(a.x*sc), f2bf(a.y*sc), f2bf(a.z*sc), f2bf(a.w*sc));
        *(ushort4*)&as[ar][ac + j*4] = u;
      }
    }
    { const bf16x8* s0 = (const bf16x8*)&But[(size_t)(n0+br)*DD + k0 + bc];
      *(bf16x8*)&bu[br][bc]   = s0[0];
      *(bf16x8*)&bu[br][bc+8] = s0[1];
      const bf16x8* s1 = (const bf16x8*)&Bgt[(size_t)(n0+br)*DD + k0 + bc];
      *(bf16x8*)&bg[br][bc]   = s1[0];
      *(bf16x8*)&bg[br][bc+8] = s1[1];
    }
    __syncthreads();
    const int lr = l & 15, kb = (l >> 4)*8;
    #pragma unroll
    for (int kc2 = 0; kc2 < 2; ++kc2){
      bf16x8 af0 = *(const bf16x8*)&as[w*32 + lr][kc2*32 + kb];
      bf16x8 af1 = *(const bf16x8*)&as[w*32 + 16 + lr][kc2*32 + kb];
      #pragma unroll
      for (int nt = 0; nt < 4; ++nt){
        bf16x8 b0 = *(const bf16x8*)&bu[nt*16 + lr][kc2*32 + kb];
        accu[0][nt] = __builtin_amdgcn_mfma_f32_16x16x32_bf16(af0, b0, accu[0][nt], 0, 0, 0);
        accu[1][nt] = __builtin_amdgcn_mfma_f32_16x16x32_bf16(af1, b0, accu[1][nt], 0, 0, 0);
        bf16x8 b1 = *(const bf16x8*)&bg[nt*16 + lr][kc2*32 + kb];
        accg[0][nt] = __builtin_amdgcn_mfma_f32_16x16x32_bf16(af0, b1, accg[0][nt], 0, 0, 0);
        accg[1][nt] = __builtin_amdgcn_mfma_f32_16x16x32_bf16(af1, b1, accg[1][nt], 0, 0, 0);
      }
    }
    __syncthreads();
  }
  const int lr = l & 15;
  #pragma unroll
  for (int mt = 0; mt < 2; ++mt){
    #pragma unroll
    for (int nt = 0; nt < 4; ++nt){
      int col = n0 + nt*16 + lr;
      #pragma unroll
      for (int r = 0; r < 4; ++r){
        int row = m0 + w*32 + mt*16 + (l >> 4)*4 + r;
        Cu[(size_t)row*DIM + col] = f2bf(accu[mt][nt][r]);
        Cg[(size_t)row*DIM + col] = f2bf(accg[mt][nt][r]);
      }
    }
  }
}

// ---- Wout GEMM 64x64: fused comb + resid + per-row ssq partials ------------
__global__ void __launch_bounds__(256) k_gemm_wout(const float* __restrict__ p0,
                                                   const float* __restrict__ p1,
                                                   const unsigned short* __restrict__ Bt,
                                                   const float* __restrict__ y,
                                                   float* __restrict__ x,
                                                   float* __restrict__ rowssq){
  __shared__ unsigned short as[64][72];
  __shared__ unsigned short bs[64][72];
  const int tid = threadIdx.x;
  const int w = tid >> 6, l = tid & 63;
  const int m0 = blockIdx.y*64, n0 = blockIdx.x*64;
  const int ar = tid >> 2, ac = (tid & 3)*16;
  f32x4 acc[4] = {};
  for (int k0 = 0; k0 < DD; k0 += 64){
    #pragma unroll
    for (int j = 0; j < 4; ++j){
      size_t off = (size_t)(m0+ar)*DD + k0 + ac + j*4;
      float4 a = *(const float4*)&p0[off];
      float4 b = *(const float4*)&p1[off];
      a.x += b.x; a.y += b.y; a.z += b.z; a.w += b.w;
      ushort4 u = make_ushort4(f2bf(a.x), f2bf(a.y), f2bf(a.z), f2bf(a.w));
      *(ushort4*)&as[ar][ac + j*4] = u;
    }
    { const bf16x8* src = (const bf16x8*)&Bt[(size_t)(n0+ar)*DD + k0 + ac];
      *(bf16x8*)&bs[ar][ac]   = src[0];
      *(bf16x8*)&bs[ar][ac+8] = src[1];
    }
    __syncthreads();
    const int mr = w*16 + (l & 15);
    const int kb = (l >> 4)*8;
    #pragma unroll
    for (int kc2 = 0; kc2 < 2; ++kc2){
      bf16x8 af = *(const bf16x8*)&as[mr][kc2*32 + kb];
      #pragma unroll
      for (int nt = 0; nt < 4; ++nt){
        bf16x8 bfr = *(const bf16x8*)&bs[nt*16 + (l & 15)][kc2*32 + kb];
        acc[nt] = __builtin_amdgcn_mfma_f32_16x16x32_bf16(af, bfr, acc[nt], 0, 0, 0);
      }
    }
    __syncthreads();
  }
  const int ROWS = BB*TT;
  float ssq[4] = {0.f, 0.f, 0.f, 0.f};
  #pragma unroll
  for (int nt = 0; nt < 4; ++nt){
    int col = n0 + nt*16 + (l & 15);
    #pragma unroll
    for (int r = 0; r < 4; ++r){
      int row = m0 + w*16 + (l >> 4)*4 + r;
      size_t off = (size_t)row*DD + col;
      float nv = x[off] + y[off] + acc[nt][r];
      x[off] = nv;
      ssq[r] = fmaf(nv, nv, ssq[r]);
    }
  }
  #pragma unroll
  for (int r = 0; r < 4; ++r){
    float s = ssq[r];
    s = xor1_add(s); s = xor2_add(s); s = ror4_add(s); s = ror8_add(s);
    if ((l & 15) == 0){
      int row = m0 + w*16 + (l >> 4)*4 + r;
      rowssq[(size_t)blockIdx.x*ROWS + row] = s;
    }
  }
}

// ------------ causal depthwise conv + silu gating, bf16 in/out ------------
__global__ void k_conv(const unsigned short* __restrict__ u,
                       const unsigned short* __restrict__ g,
                       const float* __restrict__ cw, const float* __restrict__ cb,
                       unsigned short* __restrict__ hh){
  int i8 = blockIdx.x*256 + threadIdx.x;
  int cg = i8 & 63;
  int bt = i8 >> 6;
  int t  = bt & (TT-1);
  int c0 = cg*8;
  float acc[8];
  { float4 b0 = *(const float4*)&cb[c0];
    float4 b1 = *(const float4*)&cb[c0+4];
    acc[0]=b0.x; acc[1]=b0.y; acc[2]=b0.z; acc[3]=b0.w;
    acc[4]=b1.x; acc[5]=b1.y; acc[6]=b1.z; acc[7]=b1.w; }
  float wts[8][4];
  #pragma unroll
  for (int i = 0; i < 8; ++i) *(float4*)&wts[i][0] = *(const float4*)&cw[(c0+i)*KW];
  #pragma unroll
  for (int j = 0; j < KW; ++j){
    int dt_ = j - (KW-1);
    if (t + dt_ >= 0){
      bf16x8 uv = *(const bf16x8*)&u[(size_t)(bt + dt_)*DIM + c0];
      #pragma unroll
      for (int i = 0; i < 8; ++i)
        acc[i] = fmaf(bf2f((unsigned short)uv[i]), wts[i][j], acc[i]);
    }
  }
  bf16x8 gv = *(const bf16x8*)&g[(size_t)bt*DIM + c0];
  bf16x8 o;
  #pragma unroll
  for (int i = 0; i < 8; ++i){
    float h = siluf(acc[i]);
    o[i] = (short)f2bf(siluf(bf2f((unsigned short)gv[i])) * h);
  }
  *(bf16x8*)&hh[(size_t)bt*DIM + c0] = o;
}

// ---- fused: proj + scal + rk-normalize (rk f32) ----
__global__ void __launch_bounds__(256) k_fused(const float* __restrict__ y,
    const float* __restrict__ Wg, const float* __restrict__ Wb,
    const float* __restrict__ Wa, const float* __restrict__ Wbl,
    const float* __restrict__ A_log, const float* __restrict__ dtb,
    float* __restrict__ rkb, float* __restrict__ scal){
  __shared__ float s_y[4][260];
  __shared__ float s_p[4][32];
  const int wv = threadIdx.x >> 6, l = threadIdx.x & 63;
  const int row = blockIdx.x*4 + wv;

  float4 yv = *(const float4*)&y[(size_t)row*DD + l*4];
  *(float4*)&s_y[wv][l*4] = yv;

  float ss = yv.x*yv.x + yv.y*yv.y + yv.z*yv.z + yv.w*yv.w;
  ss = xor1_add(ss); ss = xor2_add(ss);
  ss = ror4_add(ss); ss = ror8_add(ss);
  float inv = 1.f / fmaxf(sqrtf(ss), 1e-12f);
  float4 rv; rv.x = yv.x*inv; rv.y = yv.y*inv; rv.z = yv.z*inv; rv.w = yv.w*inv;
  *(float4*)&rkb[(size_t)row*DD + l*4] = rv;

  __syncthreads();

  const int j = (l < 28) ? l : 27;
  const float* wp; int stride;
  if (j < 4){ wp = Wg + j; stride = HH; }
  else if (j < 12){ int m=(j-4)>>2, h=(j-4)&3; wp = Wb + (size_t)m*DD*HH + h; stride = HH; }
  else if (j < 20){ int m=(j-12)>>2, h=(j-12)&3; wp = Wa + (size_t)m*DD*HH + h; stride = HH; }
  else { wp = Wbl + (j-20); stride = HH*MM; }
  float a0=0.f,a1=0.f,a2=0.f,a3=0.f;
  #pragma unroll 4
  for (int k = 0; k < DD; k += 4){
    a0 = fmaf(s_y[wv][k+0], wp[(k+0)*stride], a0);
    a1 = fmaf(s_y[wv][k+1], wp[(k+1)*stride], a1);
    a2 = fmaf(s_y[wv][k+2], wp[(k+2)*stride], a2);
    a3 = fmaf(s_y[wv][k+3], wp[(k+3)*stride], a3);
  }
  if (l < 28) s_p[wv][l] = (a0+a1)+(a2+a3);

  __syncthreads();

  if (l < 8){
    int m = l >> 2, h = l & 3;
    float gs  = sigf(s_p[wv][h]);
    float btv = sigf(s_p[wv][4 + m*4 + h]);
    float sp  = s_p[wv][12 + m*4 + h] + dtb[m*HH + h];
    sp = (sp > 15.f) ? sp : log1pf(__expf(sp));
    float dc  = __expf(-__expf(A_log[m*HH + h]) * sp);
    float l0 = s_p[wv][20 + h*2], l1 = s_p[wv][20 + h*2 + 1];
    float mx = fmaxf(l0, l1);
    float e0 = __expf(l0-mx), e1 = __expf(l1-mx);
    float bl = (m ? e1 : e0) / (e0 + e1);
    float4 o; o.x = dc; o.y = btv; o.z = bl*gs; o.w = 0.f;
    *(float4*)&scal[((size_t)row*MM + m)*(HH*4) + h*4] = o;
  }
}

// ---------------- sequential delta-memory scan, d-split-16 (R13) ----------
#define SSTEP(T_, WK, RK, PF, VB, SB) { \
  const float dc = SB.x, btv = SB.y, blg = SB.z; \
  const float v = VB; \
  { const int tn_ = ((T_)+2 < 64) ? (T_)+2 : 63; \
    PF = *(const float4*)&s_rk[p][tn_][dbase]; \
    VB = bf2f(s_v[p][tn_][vidx]); \
    SB = *(const float4*)&s_sc[p][tn_][0]; } \
  const float err = (v - dc*rrc)*btv; \
  float rr0=0.f, rr1=0.f; \
  { const float4 rp = WK; const float4 rc = RK; \
    float w0,w1,w2,w3,c0,c1,c2,c3; \
    if (ROT == 0){ w0=rp.x; w1=rp.y; w2=rp.z; w3=rp.w; c0=rc.x; c1=rc.y; c2=rc.z; c3=rc.w; } \
    else { w0=-rp.y; w1=rp.x; w2=-rp.w; w3=rp.z; c0=-rc.y; c1=rc.x; c2=-rc.w; c3=rc.z; } \
    S[0] = fmaf(S[0], dc, w0*err); rr0 = fmaf(S[0], c0, rr0); \
    S[1] = fmaf(S[1], dc, w1*err); rr1 = fmaf(S[1], c1, rr1); \
    S[2] = fmaf(S[2], dc, w2*err); rr0 = fmaf(S[2], c2, rr0); \
    S[3] = fmaf(S[3], dc, w3*err); rr1 = fmaf(S[3], c3, rr1); } \
  float rr = rr0 + rr1; \
  rr = xor1_add(rr); rr = xor2_add(rr); rr = ror4_add(rr); rr = ror8_add(rr); \
  rrc = rr; \
  if (seg == 0) part[(size_t)(rowchunk + (T_))*DD + h*HDIM + kq4*4 + klocal] = blg*rr; \
}

template<int ROT>
__device__ __forceinline__ void scan_body(int b, int h, int kq4, int l,
    const unsigned short* __restrict__ vals, const float* __restrict__ rkb,
    const float* __restrict__ scal, float* __restrict__ part,
    float (*s_rk)[64][64], unsigned short (*s_v)[64][8], float (*s_sc)[64][4])
{
  const int seg = l & 15, klocal = l >> 4;
  const int dbase = seg*4;
  const int vidx = (kq4 & 1)*4 + klocal;
  const int kq8 = kq4 >> 1;
  const int rowbase = b*TT;

  float S[4];
  #pragma unroll
  for (int j = 0; j < 4; ++j) S[j] = 0.f;
  const float4 Z = make_float4(0.f,0.f,0.f,0.f);
  float4 rb0 = Z, rb1 = Z, rb2 = Z, rb3 = Z;
  float vb0 = 0.f, vb1 = 0.f;
  float4 sb0 = Z, sb1 = Z;
  float rrc = 0.f;

  auto stage = [&](int c, int pbuf){
    const int r0 = rowbase + c*64;
    #pragma unroll
    for (int i = 0; i < 16; ++i){
      const float* g = rkb + (size_t)(r0 + i*4 + (l>>4))*DD + h*HDIM + (l&15)*4;
      gl_lds16(g, &s_rk[pbuf][i*4][0]);
    }
    { const unsigned short* g = vals + ((size_t)(r0 + l)*MM + ROT)*DD + h*HDIM + kq8*8;
      gl_lds16(g, &s_v[pbuf][0][0]); }
    { const float* g = scal + ((size_t)(r0 + l)*MM + ROT)*(HH*4) + h*4;
      gl_lds16(g, &s_sc[pbuf][0][0]); }
  };

  stage(0, 0);
  for (int c = 0; c < TT/64; ++c){
    const int p = c & 1;
    __syncthreads();
    if (c + 1 < TT/64) stage(c+1, p^1);
    rb0 = *(const float4*)&s_rk[p][0][dbase];
    rb1 = *(const float4*)&s_rk[p][1][dbase];
    vb0 = bf2f(s_v[p][0][vidx]); vb1 = bf2f(s_v[p][1][vidx]);
    sb0 = *(const float4*)&s_sc[p][0][0]; sb1 = *(const float4*)&s_sc[p][1][0];
    const int rowchunk = rowbase + c*64;
    for (int tt = 0; tt < 64; tt += 4){
      SSTEP(tt+0, rb3, rb0, rb2, vb0, sb0)
      SSTEP(tt+1, rb0, rb1, rb3, vb1, sb1)
      SSTEP(tt+2, rb1, rb2, rb0, vb0, sb0)
      SSTEP(tt+3, rb2, rb3, rb1, vb1, sb1)
    }
  }
}

__global__ void __launch_bounds__(64) k_scan(const unsigned short* __restrict__ vals,
                                             const float* __restrict__ rkb,
                                             const float* __restrict__ scal,
                                             float* __restrict__ partials){
  __shared__ float s_rk[2][64][64];
  __shared__ unsigned short s_v[2][64][8];
  __shared__ float s_sc[2][64][4];
  const int bi = blockIdx.x;
  const int kq4 = bi & 15;
  const int m  = (bi >> 4) & 1;
  const int h  = (bi >> 5) & 3;
  const int b  = bi >> 7;
  float* part = partials + (size_t)m*(BB*TT*DD);
  if (m == 0) scan_body<0>(b, h, kq4, threadIdx.x, vals, rkb, scal, part, s_rk, s_v, s_sc);
  else        scan_body<1>(b, h, kq4, threadIdx.x, vals, rkb, scal, part, s_rk, s_v, s_sc);
}

extern "C" void kernel_launch(void* const* d_in, const int* in_sizes, int n_in,
                              void* d_out, int out_size, void* d_ws, size_t ws_size,
                              hipStream_t stream){
  const int*   ids   = (const int*)d_in[0];
  const float* emb   = (const float*)d_in[1];
  const float* normw = (const float*)d_in[2];
  const float* Wup   = (const float*)d_in[3];
  const float* Wgate = (const float*)d_in[4];
  const float* Wdown = (const float*)d_in[5];
  const float* convw = (const float*)d_in[6];
  const float* convb = (const float*)d_in[7];
  const float* Wv    = (const float*)d_in[8];
  const float* Wg    = (const float*)d_in[9];
  const float* Wb    = (const float*)d_in[10];
  const float* Wa    = (const float*)d_in[11];
  const float* A_log = (const float*)d_in[12];
  const float* dtb   = (const float*)d_in[13];
  const float* Wbl   = (const float*)d_in[14];
  const float* Wout  = (const float*)d_in[15];
  const float* fnw   = (const float*)d_in[16];
  float* out = (float*)d_out;

  const int ROWS = BB*TT;              // 4096
  const size_t MEG = 1u << 20;
  float* ws   = (float*)d_ws;
  float* x    = ws;                        // 1M f32
  unsigned short* nyb = (unsigned short*)(x + MEG);    // 1M bf16
  float* big1 = x + MEG + MEG/2;           // 2M floats
  float* big2 = big1 + 2*MEG;              // 2M f32: partials
  float* y    = big2 + 2*MEG;              // 1M f32
  float* rkb  = y    + MEG;                // 1M f32
  float* scal = rkb  + MEG;                // 128K f32
  float* rowssq = scal + (1u<<17);         // 4*4096 f32
  unsigned short* wbf = (unsigned short*)(rowssq + 4*ROWS);

  unsigned short* ub  = (unsigned short*)big1;
  unsigned short* gb  = (unsigned short*)(big1 + MEG);
  unsigned short* valsb = ub;

  { int total = 2*LWB + VV*DD;
    k_cvt<<<(total + 255)/256, 256, 0, stream>>>(Wup, Wgate, Wdown, Wv, Wout, emb,
                                                 normw, fnw, wbf); }

  k_embed_norm<<<ROWS/4, 256, 0, stream>>>(ids, emb, normw, x, nyb);

  for (int l = 0; l < LL; ++l){
    unsigned short* wl = wbf + (size_t)l*LWB;
    unsigned short* upT   = wl;
    unsigned short* gateT = wl + 131072;
    unsigned short* downT = wl + 262144;
    unsigned short* wvT   = wl + 393216;
    unsigned short* woutT = wl + 524288;

    if (l == 0)
      k_gemm_up<<<dim3(DIM/64, ROWS/128), 256, 0, stream>>>(nyb, upT, gateT, ub, gb);
    else
      k_gemm_up2<<<dim3(DIM/64, ROWS/128), 256, 0, stream>>>(x, rowssq, upT, gateT, ub, gb);
    k_conv<<<(ROWS*DIM/8)/256, 256, 0, stream>>>(ub, gb, convw + l*DIM*KW, convb + l*DIM, gb);
    k_gemm64<2><<<dim3(DD/64, ROWS/64), 256, 0, stream>>>(gb, downT, y, nyb, DD, DIM);
    k_gemm128<1><<<dim3(DIM/64, ROWS/128), 256, 0, stream>>>(nyb, wvT, nullptr, valsb, DIM, DD);
    k_fused<<<ROWS/4, 256, 0, stream>>>(y, Wg + l*DD*HH, Wb + (size_t)l*MM*DD*HH,
                                        Wa + (size_t)l*MM*DD*HH, Wbl + l*DD*HH*MM,
                                        A_log + l*MM*HH, dtb + l*MM*HH, rkb, scal);
    k_scan<<<BB*HH*MM*16, 64, 0, stream>>>(valsb, rkb, scal, big2);
    k_gemm_wout<<<dim3(DD/64, ROWS/64), 256, 0, stream>>>(big2, big2 + MEG, woutT, y, x, rowssq);
  }

  unsigned short* embT = wbf + 2*LWB;   // [272][256] bf16 (fnw folded)
  k_gemmlogit<<<dim3((VV+63)/64, ROWS/64), 256, 0, stream>>>(x, rowssq, embT, out, VV, DD);
}

// Round 19
// 274.491 us; speedup vs baseline: 1.0814x; 1.0381x over previous
//
#include <hip/hip_runtime.h>
#include <math.h>

#define BB 8
#define TT 512
#define DD 256
#define DIM 512
#define KW 4
#define MM 2
#define HH 4
#define HDIM 64
#define LL 2
#define VV 272

typedef __attribute__((ext_vector_type(8))) short bf16x8;
typedef __attribute__((ext_vector_type(4))) float f32x4;

__device__ __forceinline__ float sigf(float x){ return 1.f/(1.f+__expf(-x)); }
__device__ __forceinline__ float siluf(float x){ return x/(1.f+__expf(-x)); }

__device__ __forceinline__ unsigned short f2bf(float f){
  unsigned int u = __float_as_uint(f);
  unsigned int r = (u + 0x7FFFu + ((u >> 16) & 1u)) >> 16;
  return (unsigned short)r;
}
__device__ __forceinline__ float bf2f(unsigned short s){
  return __uint_as_float(((unsigned int)s) << 16);
}

// DPP reduces (no DS ops)
__device__ __forceinline__ float xor1_add(float x){
  int y = __builtin_amdgcn_update_dpp(0, __float_as_int(x), 0xB1, 0xF, 0xF, true);
  return x + __int_as_float(y);
}
__device__ __forceinline__ float xor2_add(float x){
  int y = __builtin_amdgcn_update_dpp(0, __float_as_int(x), 0x4E, 0xF, 0xF, true);
  return x + __int_as_float(y);
}
__device__ __forceinline__ float ror4_add(float x){
  int y = __builtin_amdgcn_update_dpp(0, __float_as_int(x), 0x124, 0xF, 0xF, true);
  return x + __int_as_float(y);
}
__device__ __forceinline__ float ror8_add(float x){
  int y = __builtin_amdgcn_update_dpp(0, __float_as_int(x), 0x128, 0xF, 0xF, true);
  return x + __int_as_float(y);
}

// async global->LDS, 16B per lane. LDS dest is wave-uniform base + lane*16.
__device__ __forceinline__ void gl_lds16(const void* g, void* l){
  __builtin_amdgcn_global_load_lds(
      (const __attribute__((address_space(1))) unsigned int*)g,
      (__attribute__((address_space(3))) unsigned int*)l,
      16, 0, 0);
}

// ---------------- weight convert + transpose to bf16 [N][K] ----------------
// Folds normw (layer 1 only) into upT/gateT, and fnw into embT.
#define LWB 589824
__global__ void k_cvt(const float* __restrict__ Wup, const float* __restrict__ Wgate,
                      const float* __restrict__ Wdown, const float* __restrict__ Wv,
                      const float* __restrict__ Wout, const float* __restrict__ emb,
                      const float* __restrict__ normw, const float* __restrict__ fnw,
                      unsigned short* __restrict__ wbf){
  int idx = blockIdx.x*256 + threadIdx.x;
  if (idx >= 2*LWB + VV*DD) return;
  float v;
  if (idx < 2*LWB){
    int l = (idx >= LWB) ? 1 : 0;
    int local = idx - l*LWB;
    if (local < 131072){ int n = local>>8, k = local&255;
      v = Wup[(size_t)l*131072 + k*DIM + n];
      if (l == 1) v *= normw[DD + k]; }
    else if (local < 262144){ local -= 131072; int n = local>>8, k = local&255;
      v = Wgate[(size_t)l*131072 + k*DIM + n];
      if (l == 1) v *= normw[DD + k]; }
    else if (local < 393216){ local -= 262144; int n = local>>9, k = local&511;
      v = Wdown[(size_t)l*131072 + k*DD + n]; }
    else if (local < 524288){ local -= 393216; int n = local>>8, k = local&255;
      v = Wv[(size_t)l*131072 + k*DIM + n]; }
    else { local -= 524288; int n = local>>8, k = local&255;
      v = Wout[(size_t)l*65536 + k*DD + n]; }
  } else {
    int k = (idx - 2*LWB) & 255;
    v = emb[idx - 2*LWB] * fnw[k];
  }
  wbf[idx] = f2bf(v);
}

// ------- fused embedding gather + rmsnorm (layer 0) ---
__global__ void __launch_bounds__(256) k_embed_norm(const int* __restrict__ ids,
                                                    const float* __restrict__ emb,
                                                    const float* __restrict__ w,
                                                    float* __restrict__ x,
                                                    unsigned short* __restrict__ out){
  const int wv = threadIdx.x >> 6, l = threadIdx.x & 63;
  const int row = blockIdx.x*4 + wv;
  float4 v = *(const float4*)&emb[(size_t)ids[row]*DD + l*4];
  *(float4*)&x[(size_t)row*DD + l*4] = v;
  float ss = v.x*v.x + v.y*v.y + v.z*v.z + v.w*v.w;
  #pragma unroll
  for (int o = 32; o > 0; o >>= 1) ss += __shfl_xor(ss, o, 64);
  float sc = rsqrtf(ss*(1.f/DD) + 1e-6f);
  float4 wvv = *(const float4*)&w[l*4];
  ushort4 r;
  r.x = f2bf(v.x*sc*wvv.x); r.y = f2bf(v.y*sc*wvv.y);
  r.z = f2bf(v.z*sc*wvv.z); r.w = f2bf(v.w*sc*wvv.w);
  *(ushort4*)&out[(size_t)row*DD + l*4] = r;
}

// -------- bf16 GEMM 64x64 tile (4 waves) --------
template<int MODE>
__global__ void __launch_bounds__(256) k_gemm64(const unsigned short* __restrict__ A,
                                                const unsigned short* __restrict__ Bt,
                                                float* __restrict__ Cf,
                                                unsigned short* __restrict__ Cb,
                                                int N, int K){
  __shared__ unsigned short as[64][72];
  __shared__ unsigned short bs[64][72];
  const int tid = threadIdx.x;
  const int w = tid >> 6, l = tid & 63;
  const int m0 = blockIdx.y*64, n0 = blockIdx.x*64;
  const int ar = tid >> 2, ac = (tid & 3)*16;
  f32x4 acc[4] = {};
  for (int k0 = 0; k0 < K; k0 += 64){
    { const bf16x8* src = (const bf16x8*)&A[(size_t)(m0+ar)*K + k0 + ac];
      *(bf16x8*)&as[ar][ac]   = src[0];
      *(bf16x8*)&as[ar][ac+8] = src[1];
    }
    { int n = n0 + ar;
      bf16x8 z; z = (bf16x8)(short)0;
      bf16x8 b0 = z, b1 = z;
      if (n < N){
        const bf16x8* src = (const bf16x8*)&Bt[(size_t)n*K + k0 + ac];
        b0 = src[0]; b1 = src[1];
      }
      *(bf16x8*)&bs[ar][ac]   = b0;
      *(bf16x8*)&bs[ar][ac+8] = b1;
    }
    __syncthreads();
    const int mr = w*16 + (l & 15);
    const int kb = (l >> 4)*8;
    #pragma unroll
    for (int kc2 = 0; kc2 < 2; ++kc2){
      bf16x8 af = *(const bf16x8*)&as[mr][kc2*32 + kb];
      #pragma unroll
      for (int nt = 0; nt < 4; ++nt){
        bf16x8 bfr = *(const bf16x8*)&bs[nt*16 + (l & 15)][kc2*32 + kb];
        acc[nt] = __builtin_amdgcn_mfma_f32_16x16x32_bf16(af, bfr, acc[nt], 0, 0, 0);
      }
    }
    __syncthreads();
  }
  #pragma unroll
  for (int nt = 0; nt < 4; ++nt){
    int col = n0 + nt*16 + (l & 15);
    if (col < N){
      #pragma unroll
      for (int r = 0; r < 4; ++r){
        int row = m0 + w*16 + (l >> 4)*4 + r;
        if (MODE == 0 || MODE == 2) Cf[(size_t)row*N + col] = acc[nt][r];
        if (MODE == 1 || MODE == 2) Cb[(size_t)row*N + col] = f2bf(acc[nt][r]);
      }
    }
  }
}

// -------- logits GEMM: A = x (f32) normalized on the fly via rowssq ---------
__global__ void __launch_bounds__(256) k_gemmlogit(const float* __restrict__ X,
                                                   const float* __restrict__ pssq,
                                                   const unsigned short* __restrict__ Bt,
                                                   float* __restrict__ Cf,
                                                   int N, int K){
  __shared__ unsigned short as[64][72];
  __shared__ unsigned short bs[64][72];
  const int tid = threadIdx.x;
  const int w = tid >> 6, l = tid & 63;
  const int m0 = blockIdx.y*64, n0 = blockIdx.x*64;
  const int ar = tid >> 2, ac = (tid & 3)*16;
  const int arow = m0 + ar;
  const int ROWS = BB*TT;
  float ssq = pssq[arow] + pssq[ROWS + arow] + pssq[2*ROWS + arow] + pssq[3*ROWS + arow];
  const float sc = rsqrtf(ssq*(1.f/DD) + 1e-6f);
  f32x4 acc[4] = {};
  for (int k0 = 0; k0 < K; k0 += 64){
    { const float* src = &X[(size_t)arow*K + k0 + ac];
      #pragma unroll
      for (int j = 0; j < 4; ++j){
        float4 a = *(const float4*)&src[j*4];
        ushort4 u = make_ushort4(f2bf(a.x*sc), f2bf(a.y*sc), f2bf(a.z*sc), f2bf(a.w*sc));
        *(ushort4*)&as[ar][ac + j*4] = u;
      }
    }
    { int n = n0 + ar;
      bf16x8 z; z = (bf16x8)(short)0;
      bf16x8 b0 = z, b1 = z;
      if (n < N){
        const bf16x8* src = (const bf16x8*)&Bt[(size_t)n*K + k0 + ac];
        b0 = src[0]; b1 = src[1];
      }
      *(bf16x8*)&bs[ar][ac]   = b0;
      *(bf16x8*)&bs[ar][ac+8] = b1;
    }
    __syncthreads();
    const int mr = w*16 + (l & 15);
    const int kb = (l >> 4)*8;
    #pragma unroll
    for (int kc2 = 0; kc2 < 2; ++kc2){
      bf16x8 af = *(const bf16x8*)&as[mr][kc2*32 + kb];
      #pragma unroll
      for (int nt = 0; nt < 4; ++nt){
        bf16x8 bfr = *(const bf16x8*)&bs[nt*16 + (l & 15)][kc2*32 + kb];
        acc[nt] = __builtin_amdgcn_mfma_f32_16x16x32_bf16(af, bfr, acc[nt], 0, 0, 0);
      }
    }
    __syncthreads();
  }
  #pragma unroll
  for (int nt = 0; nt < 4; ++nt){
    int col = n0 + nt*16 + (l & 15);
    if (col < N){
      #pragma unroll
      for (int r = 0; r < 4; ++r){
        int row = m0 + w*16 + (l >> 4)*4 + r;
        Cf[(size_t)row*N + col] = acc[nt][r];
      }
    }
  }
}

// -------- bf16 GEMM 128x64 tile (4 waves) --------
template<int MODE>
__global__ void __launch_bounds__(256) k_gemm128(const unsigned short* __restrict__ A,
                                                 const unsigned short* __restrict__ Bt,
                                                 float* __restrict__ Cf,
                                                 unsigned short* __restrict__ Cb,
                                                 int N, int K){
  __shared__ unsigned short as[128][72];
  __shared__ unsigned short bs[64][72];
  const int tid = threadIdx.x;
  const int w = tid >> 6, l = tid & 63;
  const int m0 = blockIdx.y*128, n0 = blockIdx.x*64;
  const int ar = tid >> 1, ac = (tid & 1)*32;
  const int br = tid >> 2, bc = (tid & 3)*16;
  f32x4 acc[2][4] = {};
  for (int k0 = 0; k0 < K; k0 += 64){
    { const bf16x8* src = (const bf16x8*)&A[(size_t)(m0+ar)*K + k0 + ac];
      *(bf16x8*)&as[ar][ac]    = src[0];
      *(bf16x8*)&as[ar][ac+8]  = src[1];
      *(bf16x8*)&as[ar][ac+16] = src[2];
      *(bf16x8*)&as[ar][ac+24] = src[3];
    }
    { int n = n0 + br;
      bf16x8 z; z = (bf16x8)(short)0;
      bf16x8 b0 = z, b1 = z;
      if (n < N){
        const bf16x8* s = (const bf16x8*)&Bt[(size_t)n*K + k0 + bc];
        b0 = s[0]; b1 = s[1];
      }
      *(bf16x8*)&bs[br][bc]   = b0;
      *(bf16x8*)&bs[br][bc+8] = b1;
    }
    __syncthreads();
    const int lr = l & 15, kb = (l >> 4)*8;
    #pragma unroll
    for (int kc2 = 0; kc2 < 2; ++kc2){
      bf16x8 af0 = *(const bf16x8*)&as[w*32 + lr][kc2*32 + kb];
      bf16x8 af1 = *(const bf16x8*)&as[w*32 + 16 + lr][kc2*32 + kb];
      #pragma unroll
      for (int nt = 0; nt < 4; ++nt){
        bf16x8 bfr = *(const bf16x8*)&bs[nt*16 + lr][kc2*32 + kb];
        acc[0][nt] = __builtin_amdgcn_mfma_f32_16x16x32_bf16(af0, bfr, acc[0][nt], 0, 0, 0);
        acc[1][nt] = __builtin_amdgcn_mfma_f32_16x16x32_bf16(af1, bfr, acc[1][nt], 0, 0, 0);
      }
    }
    __syncthreads();
  }
  const int lr = l & 15;
  #pragma unroll
  for (int mt = 0; mt < 2; ++mt){
    #pragma unroll
    for (int nt = 0; nt < 4; ++nt){
      int col = n0 + nt*16 + lr;
      if (col < N){
        #pragma unroll
        for (int r = 0; r < 4; ++r){
          int row = m0 + w*32 + mt*16 + (l >> 4)*4 + r;
          if (MODE == 0 || MODE == 2) Cf[(size_t)row*N + col] = acc[mt][nt][r];
          if (MODE == 1 || MODE == 2) Cb[(size_t)row*N + col] = f2bf(acc[mt][nt][r]);
        }
      }
    }
  }
}

// ---- fused dual up/gate GEMM + causal conv + silu gating -> hh -------------
// L=0: A = nyb (bf16). L=1: A = x (f32) normalized via rowssq (normw folded
// into weights). Conv boundary rows (t0>0) recomputed in-block via scalar dots.
template<int L>
__global__ void __launch_bounds__(256) k_gemm_upc(
    const unsigned short* __restrict__ Anyb,
    const float* __restrict__ X, const float* __restrict__ pssq,
    const unsigned short* __restrict__ But,
    const unsigned short* __restrict__ Bgt,
    const float* __restrict__ cw, const float* __restrict__ cb,
    unsigned short* __restrict__ Chh)
{
  __shared__ unsigned short as[128][72];
  __shared__ unsigned short bu[64][72];
  __shared__ unsigned short bg[64][72];
  __shared__ unsigned short s_ub[132][68];  // u rows m0-3..m0+127 -> idx 0..130
  __shared__ float s_cw[64][4];
  __shared__ float s_cb[64];
  const int tid = threadIdx.x;
  const int w = tid >> 6, l = tid & 63;
  const int m0 = blockIdx.y*128, n0 = blockIdx.x*64;
  const int ar = tid >> 1, ac = (tid & 1)*32;
  const int br = tid >> 2, bc = (tid & 3)*16;
  const int ROWS = BB*TT;
  const int t0 = m0 & (TT-1);

  float scA = 1.f;
  if (L == 1){
    const int arow = m0 + ar;
    float ssq = pssq[arow] + pssq[ROWS + arow] + pssq[2*ROWS + arow] + pssq[3*ROWS + arow];
    scA = rsqrtf(ssq*(1.f/DD) + 1e-6f);
  }

  // boundary u rows (3 rows x 64 cols), scalar dots; zero at batch start
  if (tid < 192){
    int i = tid >> 6;          // 0..2 -> global row m0-3+i
    int c = tid & 63;
    float acc = 0.f;
    if (t0 != 0){
      int grow = m0 - 3 + i;
      const unsigned short* bptr = &But[(size_t)(n0+c)*DD];
      if (L == 0){
        const unsigned short* a = &Anyb[(size_t)grow*DD];
        for (int k = 0; k < DD; k += 8){
          bf16x8 av = *(const bf16x8*)&a[k];
          bf16x8 bv = *(const bf16x8*)&bptr[k];
          #pragma unroll
          for (int e = 0; e < 8; ++e)
            acc = fmaf(bf2f((unsigned short)av[e]), bf2f((unsigned short)bv[e]), acc);
        }
      } else {
        float ssq = pssq[grow] + pssq[ROWS + grow] + pssq[2*ROWS + grow] + pssq[3*ROWS + grow];
        float sc = rsqrtf(ssq*(1.f/DD) + 1e-6f);
        const float* a = &X[(size_t)grow*DD];
        for (int k = 0; k < DD; k += 4){
          float4 av = *(const float4*)&a[k];
          #pragma unroll
          for (int e = 0; e < 4; ++e){
            float ae = bf2f(f2bf(((const float*)&av)[e]*sc));
            acc = fmaf(ae, bf2f(bptr[k+e]), acc);
          }
        }
      }
    }
    s_ub[tid >> 6][tid & 63] = (t0 != 0) ? f2bf(acc) : (unsigned short)0;
  }
  if (tid < 64){
    *(float4*)&s_cw[tid][0] = *(const float4*)&cw[(n0+tid)*KW];
    s_cb[tid] = cb[n0+tid];
  }

  f32x4 accu[2][4] = {}; f32x4 accg[2][4] = {};
  for (int k0 = 0; k0 < DD; k0 += 64){
    if (L == 0){
      const bf16x8* src = (const bf16x8*)&Anyb[(size_t)(m0+ar)*DD + k0 + ac];
      *(bf16x8*)&as[ar][ac]    = src[0];
      *(bf16x8*)&as[ar][ac+8]  = src[1];
      *(bf16x8*)&as[ar][ac+16] = src[2];
      *(bf16x8*)&as[ar][ac+24] = src[3];
    } else {
      const float* src = &X[(size_t)(m0+ar)*DD + k0 + ac];
      #pragma unroll
      for (int j = 0; j < 8; ++j){
        float4 a = *(const float4*)&src[j*4];
        ushort4 u = make_ushort4(f2bf(a.x*scA), f2bf(a.y*scA), f2bf(a.z*scA), f2bf(a.w*scA));
        *(ushort4*)&as[ar][ac + j*4] = u;
      }
    }
    { const bf16x8* s0 = (const bf16x8*)&But[(size_t)(n0+br)*DD + k0 + bc];
      *(bf16x8*)&bu[br][bc]   = s0[0];
      *(bf16x8*)&bu[br][bc+8] = s0[1];
      const bf16x8* s1 = (const bf16x8*)&Bgt[(size_t)(n0+br)*DD + k0 + bc];
      *(bf16x8*)&bg[br][bc]   = s1[0];
      *(bf16x8*)&bg[br][bc+8] = s1[1];
    }
    __syncthreads();
    const int lr = l & 15, kb = (l >> 4)*8;
    #pragma unroll
    for (int kc2 = 0; kc2 < 2; ++kc2){
      bf16x8 af0 = *(const bf16x8*)&as[w*32 + lr][kc2*32 + kb];
      bf16x8 af1 = *(const bf16x8*)&as[w*32 + 16 + lr][kc2*32 + kb];
      #pragma unroll
      for (int nt = 0; nt < 4; ++nt){
        bf16x8 b0 = *(const bf16x8*)&bu[nt*16 + lr][kc2*32 + kb];
        accu[0][nt] = __builtin_amdgcn_mfma_f32_16x16x32_bf16(af0, b0, accu[0][nt], 0, 0, 0);
        accu[1][nt] = __builtin_amdgcn_mfma_f32_16x16x32_bf16(af1, b0, accu[1][nt], 0, 0, 0);
        bf16x8 b1 = *(const bf16x8*)&bg[nt*16 + lr][kc2*32 + kb];
        accg[0][nt] = __builtin_amdgcn_mfma_f32_16x16x32_bf16(af0, b1, accg[0][nt], 0, 0, 0);
        accg[1][nt] = __builtin_amdgcn_mfma_f32_16x16x32_bf16(af1, b1, accg[1][nt], 0, 0, 0);
      }
    }
    __syncthreads();
  }

  // stash u fragments to LDS (bf16, matching old global round-trip rounding)
  const int lr = l & 15;
  #pragma unroll
  for (int mt = 0; mt < 2; ++mt)
    #pragma unroll
    for (int nt = 0; nt < 4; ++nt)
      #pragma unroll
      for (int r = 0; r < 4; ++r){
        int trow = w*32 + mt*16 + (l >> 4)*4 + r;
        s_ub[3 + trow][nt*16 + lr] = f2bf(accu[mt][nt][r]);
      }
  __syncthreads();

  // conv + silu gating, write hh
  #pragma unroll
  for (int mt = 0; mt < 2; ++mt)
    #pragma unroll
    for (int nt = 0; nt < 4; ++nt)
      #pragma unroll
      for (int r = 0; r < 4; ++r){
        int trow = w*32 + mt*16 + (l >> 4)*4 + r;
        int cl = nt*16 + lr;
        float a0 = s_cb[cl];
        #pragma unroll
        for (int j = 0; j < KW; ++j)
          a0 = fmaf(bf2f(s_ub[trow + j][cl]), s_cw[cl][j], a0);
        float h = siluf(a0);
        float o = siluf(accg[mt][nt][r]) * h;
        Chh[(size_t)(m0 + trow)*DIM + (n0 + cl)] = f2bf(o);
      }
}

// ---- Wout GEMM 64x64: fused comb + resid + per-row ssq partials ------------
__global__ void __launch_bounds__(256) k_gemm_wout(const float* __restrict__ p0,
                                                   const float* __restrict__ p1,
                                                   const unsigned short* __restrict__ Bt,
                                                   const float* __restrict__ y,
                                                   float* __restrict__ x,
                                                   float* __restrict__ rowssq){
  __shared__ unsigned short as[64][72];
  __shared__ unsigned short bs[64][72];
  const int tid = threadIdx.x;
  const int w = tid >> 6, l = tid & 63;
  const int m0 = blockIdx.y*64, n0 = blockIdx.x*64;
  const int ar = tid >> 2, ac = (tid & 3)*16;
  f32x4 acc[4] = {};
  for (int k0 = 0; k0 < DD; k0 += 64){
    #pragma unroll
    for (int j = 0; j < 4; ++j){
      size_t off = (size_t)(m0+ar)*DD + k0 + ac + j*4;
      float4 a = *(const float4*)&p0[off];
      float4 b = *(const float4*)&p1[off];
      a.x += b.x; a.y += b.y; a.z += b.z; a.w += b.w;
      ushort4 u = make_ushort4(f2bf(a.x), f2bf(a.y), f2bf(a.z), f2bf(a.w));
      *(ushort4*)&as[ar][ac + j*4] = u;
    }
    { const bf16x8* src = (const bf16x8*)&Bt[(size_t)(n0+ar)*DD + k0 + ac];
      *(bf16x8*)&bs[ar][ac]   = src[0];
      *(bf16x8*)&bs[ar][ac+8] = src[1];
    }
    __syncthreads();
    const int mr = w*16 + (l & 15);
    const int kb = (l >> 4)*8;
    #pragma unroll
    for (int kc2 = 0; kc2 < 2; ++kc2){
      bf16x8 af = *(const bf16x8*)&as[mr][kc2*32 + kb];
      #pragma unroll
      for (int nt = 0; nt < 4; ++nt){
        bf16x8 bfr = *(const bf16x8*)&bs[nt*16 + (l & 15)][kc2*32 + kb];
        acc[nt] = __builtin_amdgcn_mfma_f32_16x16x32_bf16(af, bfr, acc[nt], 0, 0, 0);
      }
    }
    __syncthreads();
  }
  const int ROWS = BB*TT;
  float ssq[4] = {0.f, 0.f, 0.f, 0.f};
  #pragma unroll
  for (int nt = 0; nt < 4; ++nt){
    int col = n0 + nt*16 + (l & 15);
    #pragma unroll
    for (int r = 0; r < 4; ++r){
      int row = m0 + w*16 + (l >> 4)*4 + r;
      size_t off = (size_t)row*DD + col;
      float nv = x[off] + y[off] + acc[nt][r];
      x[off] = nv;
      ssq[r] = fmaf(nv, nv, ssq[r]);
    }
  }
  #pragma unroll
  for (int r = 0; r < 4; ++r){
    float s = ssq[r];
    s = xor1_add(s); s = xor2_add(s); s = ror4_add(s); s = ror8_add(s);
    if ((l & 15) == 0){
      int row = m0 + w*16 + (l >> 4)*4 + r;
      rowssq[(size_t)blockIdx.x*ROWS + row] = s;
    }
  }
}

// ---- fused: proj + scal + rk-normalize (rk f32) ----
__global__ void __launch_bounds__(256) k_fused(const float* __restrict__ y,
    const float* __restrict__ Wg, const float* __restrict__ Wb,
    const float* __restrict__ Wa, const float* __restrict__ Wbl,
    const float* __restrict__ A_log, const float* __restrict__ dtb,
    float* __restrict__ rkb, float* __restrict__ scal){
  __shared__ float s_y[4][260];
  __shared__ float s_p[4][32];
  const int wv = threadIdx.x >> 6, l = threadIdx.x & 63;
  const int row = blockIdx.x*4 + wv;

  float4 yv = *(const float4*)&y[(size_t)row*DD + l*4];
  *(float4*)&s_y[wv][l*4] = yv;

  float ss = yv.x*yv.x + yv.y*yv.y + yv.z*yv.z + yv.w*yv.w;
  ss = xor1_add(ss); ss = xor2_add(ss);
  ss = ror4_add(ss); ss = ror8_add(ss);
  float inv = 1.f / fmaxf(sqrtf(ss), 1e-12f);
  float4 rv; rv.x = yv.x*inv; rv.y = yv.y*inv; rv.z = yv.z*inv; rv.w = yv.w*inv;
  *(float4*)&rkb[(size_t)row*DD + l*4] = rv;

  __syncthreads();

  const int j = (l < 28) ? l : 27;
  const float* wp; int stride;
  if (j < 4){ wp = Wg + j; stride = HH; }
  else if (j < 12){ int m=(j-4)>>2, h=(j-4)&3; wp = Wb + (size_t)m*DD*HH + h; stride = HH; }
  else if (j < 20){ int m=(j-12)>>2, h=(j-12)&3; wp = Wa + (size_t)m*DD*HH + h; stride = HH; }
  else { wp = Wbl + (j-20); stride = HH*MM; }
  float a0=0.f,a1=0.f,a2=0.f,a3=0.f;
  #pragma unroll 4
  for (int k = 0; k < DD; k += 4){
    a0 = fmaf(s_y[wv][k+0], wp[(k+0)*stride], a0);
    a1 = fmaf(s_y[wv][k+1], wp[(k+1)*stride], a1);
    a2 = fmaf(s_y[wv][k+2], wp[(k+2)*stride], a2);
    a3 = fmaf(s_y[wv][k+3], wp[(k+3)*stride], a3);
  }
  if (l < 28) s_p[wv][l] = (a0+a1)+(a2+a3);

  __syncthreads();

  if (l < 8){
    int m = l >> 2, h = l & 3;
    float gs  = sigf(s_p[wv][h]);
    float btv = sigf(s_p[wv][4 + m*4 + h]);
    float sp  = s_p[wv][12 + m*4 + h] + dtb[m*HH + h];
    sp = (sp > 15.f) ? sp : log1pf(__expf(sp));
    float dc  = __expf(-__expf(A_log[m*HH + h]) * sp);
    float l0 = s_p[wv][20 + h*2], l1 = s_p[wv][20 + h*2 + 1];
    float mx = fmaxf(l0, l1);
    float e0 = __expf(l0-mx), e1 = __expf(l1-mx);
    float bl = (m ? e1 : e0) / (e0 + e1);
    float4 o; o.x = dc; o.y = btv; o.z = bl*gs; o.w = 0.f;
    *(float4*)&scal[((size_t)row*MM + m)*(HH*4) + h*4] = o;
  }
}

// ---------------- sequential delta-memory scan, d-split-16 (R13) ----------
#define SSTEP(T_, WK, RK, PF, VB, SB) { \
  const float dc = SB.x, btv = SB.y, blg = SB.z; \
  const float v = VB; \
  { const int tn_ = ((T_)+2 < 64) ? (T_)+2 : 63; \
    PF = *(const float4*)&s_rk[p][tn_][dbase]; \
    VB = bf2f(s_v[p][tn_][vidx]); \
    SB = *(const float4*)&s_sc[p][tn_][0]; } \
  const float err = (v - dc*rrc)*btv; \
  float rr0=0.f, rr1=0.f; \
  { const float4 rp = WK; const float4 rc = RK; \
    float w0,w1,w2,w3,c0,c1,c2,c3; \
    if (ROT == 0){ w0=rp.x; w1=rp.y; w2=rp.z; w3=rp.w; c0=rc.x; c1=rc.y; c2=rc.z; c3=rc.w; } \
    else { w0=-rp.y; w1=rp.x; w2=-rp.w; w3=rp.z; c0=-rc.y; c1=rc.x; c2=-rc.w; c3=rc.z; } \
    S[0] = fmaf(S[0], dc, w0*err); rr0 = fmaf(S[0], c0, rr0); \
    S[1] = fmaf(S[1], dc, w1*err); rr1 = fmaf(S[1], c1, rr1); \
    S[2] = fmaf(S[2], dc, w2*err); rr0 = fmaf(S[2], c2, rr0); \
    S[3] = fmaf(S[3], dc, w3*err); rr1 = fmaf(S[3], c3, rr1); } \
  float rr = rr0 + rr1; \
  rr = xor1_add(rr); rr = xor2_add(rr); rr = ror4_add(rr); rr = ror8_add(rr); \
  rrc = rr; \
  if (seg == 0) part[(size_t)(rowchunk + (T_))*DD + h*HDIM + kq4*4 + klocal] = blg*rr; \
}

template<int ROT>
__device__ __forceinline__ void scan_body(int b, int h, int kq4, int l,
    const unsigned short* __restrict__ vals, const float* __restrict__ rkb,
    const float* __restrict__ scal, float* __restrict__ part,
    float (*s_rk)[64][64], unsigned short (*s_v)[64][8], float (*s_sc)[64][4])
{
  const int seg = l & 15, klocal = l >> 4;
  const int dbase = seg*4;
  const int vidx = (kq4 & 1)*4 + klocal;
  const int kq8 = kq4 >> 1;
  const int rowbase = b*TT;

  float S[4];
  #pragma unroll
  for (int j = 0; j < 4; ++j) S[j] = 0.f;
  const float4 Z = make_float4(0.f,0.f,0.f,0.f);
  float4 rb0 = Z, rb1 = Z, rb2 = Z, rb3 = Z;
  float vb0 = 0.f, vb1 = 0.f;
  float4 sb0 = Z, sb1 = Z;
  float rrc = 0.f;

  auto stage = [&](int c, int pbuf){
    const int r0 = rowbase + c*64;
    #pragma unroll
    for (int i = 0; i < 16; ++i){
      const float* g = rkb + (size_t)(r0 + i*4 + (l>>4))*DD + h*HDIM + (l&15)*4;
      gl_lds16(g, &s_rk[pbuf][i*4][0]);
    }
    { const unsigned short* g = vals + ((size_t)(r0 + l)*MM + ROT)*DD + h*HDIM + kq8*8;
      gl_lds16(g, &s_v[pbuf][0][0]); }
    { const float* g = scal + ((size_t)(r0 + l)*MM + ROT)*(HH*4) + h*4;
      gl_lds16(g, &s_sc[pbuf][0][0]); }
  };

  stage(0, 0);
  for (int c = 0; c < TT/64; ++c){
    const int p = c & 1;
    __syncthreads();
    if (c + 1 < TT/64) stage(c+1, p^1);
    rb0 = *(const float4*)&s_rk[p][0][dbase];
    rb1 = *(const float4*)&s_rk[p][1][dbase];
    vb0 = bf2f(s_v[p][0][vidx]); vb1 = bf2f(s_v[p][1][vidx]);
    sb0 = *(const float4*)&s_sc[p][0][0]; sb1 = *(const float4*)&s_sc[p][1][0];
    const int rowchunk = rowbase + c*64;
    for (int tt = 0; tt < 64; tt += 4){
      SSTEP(tt+0, rb3, rb0, rb2, vb0, sb0)
      SSTEP(tt+1, rb0, rb1, rb3, vb1, sb1)
      SSTEP(tt+2, rb1, rb2, rb0, vb0, sb0)
      SSTEP(tt+3, rb2, rb3, rb1, vb1, sb1)
    }
  }
}

__global__ void __launch_bounds__(64) k_scan(const unsigned short* __restrict__ vals,
                                             const float* __restrict__ rkb,
                                             const float* __restrict__ scal,
                                             float* __restrict__ partials){
  __shared__ float s_rk[2][64][64];
  __shared__ unsigned short s_v[2][64][8];
  __shared__ float s_sc[2][64][4];
  const int bi = blockIdx.x;
  const int kq4 = bi & 15;
  const int m  = (bi >> 4) & 1;
  const int h  = (bi >> 5) & 3;
  const int b  = bi >> 7;
  float* part = partials + (size_t)m*(BB*TT*DD);
  if (m == 0) scan_body<0>(b, h, kq4, threadIdx.x, vals, rkb, scal, part, s_rk, s_v, s_sc);
  else        scan_body<1>(b, h, kq4, threadIdx.x, vals, rkb, scal, part, s_rk, s_v, s_sc);
}

extern "C" void kernel_launch(void* const* d_in, const int* in_sizes, int n_in,
                              void* d_out, int out_size, void* d_ws, size_t ws_size,
                              hipStream_t stream){
  const int*   ids   = (const int*)d_in[0];
  const float* emb   = (const float*)d_in[1];
  const float* normw = (const float*)d_in[2];
  const float* Wup   = (const float*)d_in[3];
  const float* Wgate = (const float*)d_in[4];
  const float* Wdown = (const float*)d_in[5];
  const float* convw = (const float*)d_in[6];
  const float* convb = (const float*)d_in[7];
  const float* Wv    = (const float*)d_in[8];
  const float* Wg    = (const float*)d_in[9];
  const float* Wb    = (const float*)d_in[10];
  const float* Wa    = (const float*)d_in[11];
  const float* A_log = (const float*)d_in[12];
  const float* dtb   = (const float*)d_in[13];
  const float* Wbl   = (const float*)d_in[14];
  const float* Wout  = (const float*)d_in[15];
  const float* fnw   = (const float*)d_in[16];
  float* out = (float*)d_out;

  const int ROWS = BB*TT;              // 4096
  const size_t MEG = 1u << 20;
  float* ws   = (float*)d_ws;
  float* x    = ws;                        // 1M f32
  unsigned short* nyb = (unsigned short*)(x + MEG);    // 1M bf16
  float* big1 = x + MEG + MEG/2;           // 2M floats
  float* big2 = big1 + 2*MEG;              // 2M f32: partials
  float* y    = big2 + 2*MEG;              // 1M f32
  float* rkb  = y    + MEG;                // 1M f32
  float* scal = rkb  + MEG;                // 128K f32
  float* rowssq = scal + (1u<<17);         // 4*4096 f32
  unsigned short* wbf = (unsigned short*)(rowssq + 4*ROWS);

  unsigned short* gb  = (unsigned short*)(big1 + MEG);   // hh
  unsigned short* valsb = (unsigned short*)big1;

  { int total = 2*LWB + VV*DD;
    k_cvt<<<(total + 255)/256, 256, 0, stream>>>(Wup, Wgate, Wdown, Wv, Wout, emb,
                                                 normw, fnw, wbf); }

  k_embed_norm<<<ROWS/4, 256, 0, stream>>>(ids, emb, normw, x, nyb);

  for (int l = 0; l < LL; ++l){
    unsigned short* wl = wbf + (size_t)l*LWB;
    unsigned short* upT   = wl;
    unsigned short* gateT = wl + 131072;
    unsigned short* downT = wl + 262144;
    unsigned short* wvT   = wl + 393216;
    unsigned short* woutT = wl + 524288;

    if (l == 0)
      k_gemm_upc<0><<<dim3(DIM/64, ROWS/128), 256, 0, stream>>>(
          nyb, nullptr, nullptr, upT, gateT, convw + l*DIM*KW, convb + l*DIM, gb);
    else
      k_gemm_upc<1><<<dim3(DIM/64, ROWS/128), 256, 0, stream>>>(
          nullptr, x, rowssq, upT, gateT, convw + l*DIM*KW, convb + l*DIM, gb);
    k_gemm64<2><<<dim3(DD/64, ROWS/64), 256, 0, stream>>>(gb, downT, y, nyb, DD, DIM);
    k_gemm128<1><<<dim3(DIM/64, ROWS/128), 256, 0, stream>>>(nyb, wvT, nullptr, valsb, DIM, DD);
    k_fused<<<ROWS/4, 256, 0, stream>>>(y, Wg + l*DD*HH, Wb + (size_t)l*MM*DD*HH,
                                        Wa + (size_t)l*MM*DD*HH, Wbl + l*DD*HH*MM,
                                        A_log + l*MM*HH, dtb + l*MM*HH, rkb, scal);
    k_scan<<<BB*HH*MM*16, 64, 0, stream>>>(valsb, rkb, scal, big2);
    k_gemm_wout<<<dim3(DD/64, ROWS/64), 256, 0, stream>>>(big2, big2 + MEG, woutT, y, x, rowssq);
  }

  unsigned short* embT = wbf + 2*LWB;   // [272][256] bf16 (fnw folded)
  k_gemmlogit<<<dim3((VV+63)/64, ROWS/64), 256, 0, stream>>>(x, rowssq, embT, out, VV, DD);
}

// Round 20
// 262.998 us; speedup vs baseline: 1.1287x; 1.0437x over previous
//
#include <hip/hip_runtime.h>
#include <math.h>

#define BB 8
#define TT 512
#define DD 256
#define DIM 512
#define KW 4
#define MM 2
#define HH 4
#define HDIM 64
#define LL 2
#define VV 272

typedef __attribute__((ext_vector_type(8))) short bf16x8;
typedef __attribute__((ext_vector_type(4))) float f32x4;

__device__ __forceinline__ float sigf(float x){ return 1.f/(1.f+__expf(-x)); }
__device__ __forceinline__ float siluf(float x){ return x/(1.f+__expf(-x)); }

__device__ __forceinline__ unsigned short f2bf(float f){
  unsigned int u = __float_as_uint(f);
  unsigned int r = (u + 0x7FFFu + ((u >> 16) & 1u)) >> 16;
  return (unsigned short)r;
}
__device__ __forceinline__ float bf2f(unsigned short s){
  return __uint_as_float(((unsigned int)s) << 16);
}

// DPP reduces (no DS ops)
__device__ __forceinline__ float xor1_add(float x){
  int y = __builtin_amdgcn_update_dpp(0, __float_as_int(x), 0xB1, 0xF, 0xF, true);
  return x + __int_as_float(y);
}
__device__ __forceinline__ float xor2_add(float x){
  int y = __builtin_amdgcn_update_dpp(0, __float_as_int(x), 0x4E, 0xF, 0xF, true);
  return x + __int_as_float(y);
}
__device__ __forceinline__ float ror4_add(float x){
  int y = __builtin_amdgcn_update_dpp(0, __float_as_int(x), 0x124, 0xF, 0xF, true);
  return x + __int_as_float(y);
}
__device__ __forceinline__ float ror8_add(float x){
  int y = __builtin_amdgcn_update_dpp(0, __float_as_int(x), 0x128, 0xF, 0xF, true);
  return x + __int_as_float(y);
}

// async global->LDS, 16B per lane. LDS dest is wave-uniform base + lane*16.
__device__ __forceinline__ void gl_lds16(const void* g, void* l){
  __builtin_amdgcn_global_load_lds(
      (const __attribute__((address_space(1))) unsigned int*)g,
      (__attribute__((address_space(3))) unsigned int*)l,
      16, 0, 0);
}

// ------- merged: weight convert/transpose (+fold norms) AND embed+rmsnorm ---
// blocks [0, 4880): cvt; blocks [4880, 5904): embed+norm (layer 0).
#define LWB 589824
#define CVTB 4880
__global__ void __launch_bounds__(256) k_init(
    const float* __restrict__ Wup, const float* __restrict__ Wgate,
    const float* __restrict__ Wdown, const float* __restrict__ Wv,
    const float* __restrict__ Wout, const float* __restrict__ emb,
    const float* __restrict__ normw, const float* __restrict__ fnw,
    unsigned short* __restrict__ wbf,
    const int* __restrict__ ids, float* __restrict__ x,
    unsigned short* __restrict__ nyb){
  if (blockIdx.x < CVTB){
    int idx = blockIdx.x*256 + threadIdx.x;
    if (idx >= 2*LWB + VV*DD) return;
    float v;
    if (idx < 2*LWB){
      int l = (idx >= LWB) ? 1 : 0;
      int local = idx - l*LWB;
      if (local < 131072){ int n = local>>8, k = local&255;
        v = Wup[(size_t)l*131072 + k*DIM + n];
        if (l == 1) v *= normw[DD + k]; }
      else if (local < 262144){ local -= 131072; int n = local>>8, k = local&255;
        v = Wgate[(size_t)l*131072 + k*DIM + n];
        if (l == 1) v *= normw[DD + k]; }
      else if (local < 393216){ local -= 262144; int n = local>>9, k = local&511;
        v = Wdown[(size_t)l*131072 + k*DD + n]; }
      else if (local < 524288){ local -= 393216; int n = local>>8, k = local&255;
        v = Wv[(size_t)l*131072 + k*DIM + n]; }
      else { local -= 524288; int n = local>>8, k = local&255;
        v = Wout[(size_t)l*65536 + k*DD + n]; }
    } else {
      int k = (idx - 2*LWB) & 255;
      v = emb[idx - 2*LWB] * fnw[k];
    }
    wbf[idx] = f2bf(v);
  } else {
    const int wv = threadIdx.x >> 6, l = threadIdx.x & 63;
    const int row = (blockIdx.x - CVTB)*4 + wv;
    float4 v = *(const float4*)&emb[(size_t)ids[row]*DD + l*4];
    *(float4*)&x[(size_t)row*DD + l*4] = v;
    float ss = v.x*v.x + v.y*v.y + v.z*v.z + v.w*v.w;
    #pragma unroll
    for (int o = 32; o > 0; o >>= 1) ss += __shfl_xor(ss, o, 64);
    float sc = rsqrtf(ss*(1.f/DD) + 1e-6f);
    float4 wvv = *(const float4*)&normw[l*4];
    ushort4 r;
    r.x = f2bf(v.x*sc*wvv.x); r.y = f2bf(v.y*sc*wvv.y);
    r.z = f2bf(v.z*sc*wvv.z); r.w = f2bf(v.w*sc*wvv.w);
    *(ushort4*)&nyb[(size_t)row*DD + l*4] = r;
  }
}

// -------- bf16 GEMM 64x64 tile (4 waves) --------
template<int MODE>
__global__ void __launch_bounds__(256) k_gemm64(const unsigned short* __restrict__ A,
                                                const unsigned short* __restrict__ Bt,
                                                float* __restrict__ Cf,
                                                unsigned short* __restrict__ Cb,
                                                int N, int K){
  __shared__ unsigned short as[64][72];
  __shared__ unsigned short bs[64][72];
  const int tid = threadIdx.x;
  const int w = tid >> 6, l = tid & 63;
  const int m0 = blockIdx.y*64, n0 = blockIdx.x*64;
  const int ar = tid >> 2, ac = (tid & 3)*16;
  f32x4 acc[4] = {};
  for (int k0 = 0; k0 < K; k0 += 64){
    { const bf16x8* src = (const bf16x8*)&A[(size_t)(m0+ar)*K + k0 + ac];
      *(bf16x8*)&as[ar][ac]   = src[0];
      *(bf16x8*)&as[ar][ac+8] = src[1];
    }
    { int n = n0 + ar;
      bf16x8 z; z = (bf16x8)(short)0;
      bf16x8 b0 = z, b1 = z;
      if (n < N){
        const bf16x8* src = (const bf16x8*)&Bt[(size_t)n*K + k0 + ac];
        b0 = src[0]; b1 = src[1];
      }
      *(bf16x8*)&bs[ar][ac]   = b0;
      *(bf16x8*)&bs[ar][ac+8] = b1;
    }
    __syncthreads();
    const int mr = w*16 + (l & 15);
    const int kb = (l >> 4)*8;
    #pragma unroll
    for (int kc2 = 0; kc2 < 2; ++kc2){
      bf16x8 af = *(const bf16x8*)&as[mr][kc2*32 + kb];
      #pragma unroll
      for (int nt = 0; nt < 4; ++nt){
        bf16x8 bfr = *(const bf16x8*)&bs[nt*16 + (l & 15)][kc2*32 + kb];
        acc[nt] = __builtin_amdgcn_mfma_f32_16x16x32_bf16(af, bfr, acc[nt], 0, 0, 0);
      }
    }
    __syncthreads();
  }
  #pragma unroll
  for (int nt = 0; nt < 4; ++nt){
    int col = n0 + nt*16 + (l & 15);
    if (col < N){
      #pragma unroll
      for (int r = 0; r < 4; ++r){
        int row = m0 + w*16 + (l >> 4)*4 + r;
        if (MODE == 0 || MODE == 2) Cf[(size_t)row*N + col] = acc[nt][r];
        if (MODE == 1 || MODE == 2) Cb[(size_t)row*N + col] = f2bf(acc[nt][r]);
      }
    }
  }
}

// -------- logits GEMM: A = x (f32) normalized on the fly via rowssq ---------
__global__ void __launch_bounds__(256) k_gemmlogit(const float* __restrict__ X,
                                                   const float* __restrict__ pssq,
                                                   const unsigned short* __restrict__ Bt,
                                                   float* __restrict__ Cf,
                                                   int N, int K){
  __shared__ unsigned short as[64][72];
  __shared__ unsigned short bs[64][72];
  const int tid = threadIdx.x;
  const int w = tid >> 6, l = tid & 63;
  const int m0 = blockIdx.y*64, n0 = blockIdx.x*64;
  const int ar = tid >> 2, ac = (tid & 3)*16;
  const int arow = m0 + ar;
  const int ROWS = BB*TT;
  float ssq = pssq[arow] + pssq[ROWS + arow] + pssq[2*ROWS + arow] + pssq[3*ROWS + arow];
  const float sc = rsqrtf(ssq*(1.f/DD) + 1e-6f);
  f32x4 acc[4] = {};
  for (int k0 = 0; k0 < K; k0 += 64){
    { const float* src = &X[(size_t)arow*K + k0 + ac];
      #pragma unroll
      for (int j = 0; j < 4; ++j){
        float4 a = *(const float4*)&src[j*4];
        ushort4 u = make_ushort4(f2bf(a.x*sc), f2bf(a.y*sc), f2bf(a.z*sc), f2bf(a.w*sc));
        *(ushort4*)&as[ar][ac + j*4] = u;
      }
    }
    { int n = n0 + ar;
      bf16x8 z; z = (bf16x8)(short)0;
      bf16x8 b0 = z, b1 = z;
      if (n < N){
        const bf16x8* src = (const bf16x8*)&Bt[(size_t)n*K + k0 + ac];
        b0 = src[0]; b1 = src[1];
      }
      *(bf16x8*)&bs[ar][ac]   = b0;
      *(bf16x8*)&bs[ar][ac+8] = b1;
    }
    __syncthreads();
    const int mr = w*16 + (l & 15);
    const int kb = (l >> 4)*8;
    #pragma unroll
    for (int kc2 = 0; kc2 < 2; ++kc2){
      bf16x8 af = *(const bf16x8*)&as[mr][kc2*32 + kb];
      #pragma unroll
      for (int nt = 0; nt < 4; ++nt){
        bf16x8 bfr = *(const bf16x8*)&bs[nt*16 + (l & 15)][kc2*32 + kb];
        acc[nt] = __builtin_amdgcn_mfma_f32_16x16x32_bf16(af, bfr, acc[nt], 0, 0, 0);
      }
    }
    __syncthreads();
  }
  #pragma unroll
  for (int nt = 0; nt < 4; ++nt){
    int col = n0 + nt*16 + (l & 15);
    if (col < N){
      #pragma unroll
      for (int r = 0; r < 4; ++r){
        int row = m0 + w*16 + (l >> 4)*4 + r;
        Cf[(size_t)row*N + col] = acc[nt][r];
      }
    }
  }
}

// ---- merged: wv GEMM (128x64 tile, bf16 out) AND fused proj/scal/rk --------
// blocks [0,256): wv — vals = nyb @ wvT^T ; blocks [256, 1280): fused.
__global__ void __launch_bounds__(256) k_wvf(
    const unsigned short* __restrict__ A, const unsigned short* __restrict__ Bt,
    unsigned short* __restrict__ Cb,
    const float* __restrict__ y,
    const float* __restrict__ Wg, const float* __restrict__ Wb,
    const float* __restrict__ Wa, const float* __restrict__ Wbl,
    const float* __restrict__ A_log, const float* __restrict__ dtb,
    float* __restrict__ rkb, float* __restrict__ scal)
{
  __shared__ __align__(16) unsigned char smem[27648];
  const int tid = threadIdx.x;
  if (blockIdx.x < 256){
    unsigned short (*as)[72] = (unsigned short (*)[72])smem;
    unsigned short (*bs)[72] = (unsigned short (*)[72])(smem + 128*72*2);
    const int w = tid >> 6, l = tid & 63;
    const int m0 = (blockIdx.x >> 3)*128, n0 = (blockIdx.x & 7)*64;
    const int ar = tid >> 1, ac = (tid & 1)*32;
    const int br = tid >> 2, bc = (tid & 3)*16;
    f32x4 acc[2][4] = {};
    for (int k0 = 0; k0 < DD; k0 += 64){
      { const bf16x8* src = (const bf16x8*)&A[(size_t)(m0+ar)*DD + k0 + ac];
        *(bf16x8*)&as[ar][ac]    = src[0];
        *(bf16x8*)&as[ar][ac+8]  = src[1];
        *(bf16x8*)&as[ar][ac+16] = src[2];
        *(bf16x8*)&as[ar][ac+24] = src[3];
      }
      { const bf16x8* s = (const bf16x8*)&Bt[(size_t)(n0+br)*DD + k0 + bc];
        *(bf16x8*)&bs[br][bc]   = s[0];
        *(bf16x8*)&bs[br][bc+8] = s[1];
      }
      __syncthreads();
      const int lr = l & 15, kb = (l >> 4)*8;
      #pragma unroll
      for (int kc2 = 0; kc2 < 2; ++kc2){
        bf16x8 af0 = *(const bf16x8*)&as[w*32 + lr][kc2*32 + kb];
        bf16x8 af1 = *(const bf16x8*)&as[w*32 + 16 + lr][kc2*32 + kb];
        #pragma unroll
        for (int nt = 0; nt < 4; ++nt){
          bf16x8 bfr = *(const bf16x8*)&bs[nt*16 + lr][kc2*32 + kb];
          acc[0][nt] = __builtin_amdgcn_mfma_f32_16x16x32_bf16(af0, bfr, acc[0][nt], 0, 0, 0);
          acc[1][nt] = __builtin_amdgcn_mfma_f32_16x16x32_bf16(af1, bfr, acc[1][nt], 0, 0, 0);
        }
      }
      __syncthreads();
    }
    const int lr = l & 15;
    #pragma unroll
    for (int mt = 0; mt < 2; ++mt)
      #pragma unroll
      for (int nt = 0; nt < 4; ++nt){
        int col = n0 + nt*16 + lr;
        #pragma unroll
        for (int r = 0; r < 4; ++r){
          int row = m0 + w*32 + mt*16 + (l >> 4)*4 + r;
          Cb[(size_t)row*DIM + col] = f2bf(acc[mt][nt][r]);
        }
      }
  } else {
    float (*s_y)[260] = (float (*)[260])smem;
    float (*s_p)[32]  = (float (*)[32])(smem + 4*260*4);
    const int wv = tid >> 6, l = tid & 63;
    const int row = (blockIdx.x - 256)*4 + wv;

    float4 yv = *(const float4*)&y[(size_t)row*DD + l*4];
    *(float4*)&s_y[wv][l*4] = yv;

    float ss = yv.x*yv.x + yv.y*yv.y + yv.z*yv.z + yv.w*yv.w;
    ss = xor1_add(ss); ss = xor2_add(ss);
    ss = ror4_add(ss); ss = ror8_add(ss);
    float inv = 1.f / fmaxf(sqrtf(ss), 1e-12f);
    float4 rv; rv.x = yv.x*inv; rv.y = yv.y*inv; rv.z = yv.z*inv; rv.w = yv.w*inv;
    *(float4*)&rkb[(size_t)row*DD + l*4] = rv;

    __syncthreads();

    const int j = (l < 28) ? l : 27;
    const float* wp; int stride;
    if (j < 4){ wp = Wg + j; stride = HH; }
    else if (j < 12){ int m=(j-4)>>2, h=(j-4)&3; wp = Wb + (size_t)m*DD*HH + h; stride = HH; }
    else if (j < 20){ int m=(j-12)>>2, h=(j-12)&3; wp = Wa + (size_t)m*DD*HH + h; stride = HH; }
    else { wp = Wbl + (j-20); stride = HH*MM; }
    float a0=0.f,a1=0.f,a2=0.f,a3=0.f;
    #pragma unroll 4
    for (int k = 0; k < DD; k += 4){
      a0 = fmaf(s_y[wv][k+0], wp[(k+0)*stride], a0);
      a1 = fmaf(s_y[wv][k+1], wp[(k+1)*stride], a1);
      a2 = fmaf(s_y[wv][k+2], wp[(k+2)*stride], a2);
      a3 = fmaf(s_y[wv][k+3], wp[(k+3)*stride], a3);
    }
    if (l < 28) s_p[wv][l] = (a0+a1)+(a2+a3);

    __syncthreads();

    if (l < 8){
      int m = l >> 2, h = l & 3;
      float gs  = sigf(s_p[wv][h]);
      float btv = sigf(s_p[wv][4 + m*4 + h]);
      float sp  = s_p[wv][12 + m*4 + h] + dtb[m*HH + h];
      sp = (sp > 15.f) ? sp : log1pf(__expf(sp));
      float dc  = __expf(-__expf(A_log[m*HH + h]) * sp);
      float l0 = s_p[wv][20 + h*2], l1 = s_p[wv][20 + h*2 + 1];
      float mx = fmaxf(l0, l1);
      float e0 = __expf(l0-mx), e1 = __expf(l1-mx);
      float bl = (m ? e1 : e0) / (e0 + e1);
      float4 o; o.x = dc; o.y = btv; o.z = bl*gs; o.w = 0.f;
      *(float4*)&scal[((size_t)row*MM + m)*(HH*4) + h*4] = o;
    }
  }
}

// ---- fused dual up/gate GEMM + causal conv + silu gating -> hh -------------
template<int L>
__global__ void __launch_bounds__(256) k_gemm_upc(
    const unsigned short* __restrict__ Anyb,
    const float* __restrict__ X, const float* __restrict__ pssq,
    const unsigned short* __restrict__ But,
    const unsigned short* __restrict__ Bgt,
    const float* __restrict__ cw, const float* __restrict__ cb,
    unsigned short* __restrict__ Chh)
{
  __shared__ unsigned short as[128][72];
  __shared__ unsigned short bu[64][72];
  __shared__ unsigned short bg[64][72];
  __shared__ unsigned short s_ub[132][68];
  __shared__ float s_cw[64][4];
  __shared__ float s_cb[64];
  const int tid = threadIdx.x;
  const int w = tid >> 6, l = tid & 63;
  const int m0 = blockIdx.y*128, n0 = blockIdx.x*64;
  const int ar = tid >> 1, ac = (tid & 1)*32;
  const int br = tid >> 2, bc = (tid & 3)*16;
  const int ROWS = BB*TT;
  const int t0 = m0 & (TT-1);

  float scA = 1.f;
  if (L == 1){
    const int arow = m0 + ar;
    float ssq = pssq[arow] + pssq[ROWS + arow] + pssq[2*ROWS + arow] + pssq[3*ROWS + arow];
    scA = rsqrtf(ssq*(1.f/DD) + 1e-6f);
  }

  if (tid < 192){
    int i = tid >> 6;
    int c = tid & 63;
    float acc = 0.f;
    if (t0 != 0){
      int grow = m0 - 3 + i;
      const unsigned short* bptr = &But[(size_t)(n0+c)*DD];
      if (L == 0){
        const unsigned short* a = &Anyb[(size_t)grow*DD];
        for (int k = 0; k < DD; k += 8){
          bf16x8 av = *(const bf16x8*)&a[k];
          bf16x8 bv = *(const bf16x8*)&bptr[k];
          #pragma unroll
          for (int e = 0; e < 8; ++e)
            acc = fmaf(bf2f((unsigned short)av[e]), bf2f((unsigned short)bv[e]), acc);
        }
      } else {
        float ssq = pssq[grow] + pssq[ROWS + grow] + pssq[2*ROWS + grow] + pssq[3*ROWS + grow];
        float sc = rsqrtf(ssq*(1.f/DD) + 1e-6f);
        const float* a = &X[(size_t)grow*DD];
        for (int k = 0; k < DD; k += 4){
          float4 av = *(const float4*)&a[k];
          #pragma unroll
          for (int e = 0; e < 4; ++e){
            float ae = bf2f(f2bf(((const float*)&av)[e]*sc));
            acc = fmaf(ae, bf2f(bptr[k+e]), acc);
          }
        }
      }
    }
    s_ub[tid >> 6][tid & 63] = (t0 != 0) ? f2bf(acc) : (unsigned short)0;
  }
  if (tid < 64){
    *(float4*)&s_cw[tid][0] = *(const float4*)&cw[(n0+tid)*KW];
    s_cb[tid] = cb[n0+tid];
  }

  f32x4 accu[2][4] = {}; f32x4 accg[2][4] = {};
  for (int k0 = 0; k0 < DD; k0 += 64){
    if (L == 0){
      const bf16x8* src = (const bf16x8*)&Anyb[(size_t)(m0+ar)*DD + k0 + ac];
      *(bf16x8*)&as[ar][ac]    = src[0];
      *(bf16x8*)&as[ar][ac+8]  = src[1];
      *(bf16x8*)&as[ar][ac+16] = src[2];
      *(bf16x8*)&as[ar][ac+24] = src[3];
    } else {
      const float* src = &X[(size_t)(m0+ar)*DD + k0 + ac];
      #pragma unroll
      for (int j = 0; j < 8; ++j){
        float4 a = *(const float4*)&src[j*4];
        ushort4 u = make_ushort4(f2bf(a.x*scA), f2bf(a.y*scA), f2bf(a.z*scA), f2bf(a.w*scA));
        *(ushort4*)&as[ar][ac + j*4] = u;
      }
    }
    { const bf16x8* s0 = (const bf16x8*)&But[(size_t)(n0+br)*DD + k0 + bc];
      *(bf16x8*)&bu[br][bc]   = s0[0];
      *(bf16x8*)&bu[br][bc+8] = s0[1];
      const bf16x8* s1 = (const bf16x8*)&Bgt[(size_t)(n0+br)*DD + k0 + bc];
      *(bf16x8*)&bg[br][bc]   = s1[0];
      *(bf16x8*)&bg[br][bc+8] = s1[1];
    }
    __syncthreads();
    const int lr = l & 15, kb = (l >> 4)*8;
    #pragma unroll
    for (int kc2 = 0; kc2 < 2; ++kc2){
      bf16x8 af0 = *(const bf16x8*)&as[w*32 + lr][kc2*32 + kb];
      bf16x8 af1 = *(const bf16x8*)&as[w*32 + 16 + lr][kc2*32 + kb];
      #pragma unroll
      for (int nt = 0; nt < 4; ++nt){
        bf16x8 b0 = *(const bf16x8*)&bu[nt*16 + lr][kc2*32 + kb];
        accu[0][nt] = __builtin_amdgcn_mfma_f32_16x16x32_bf16(af0, b0, accu[0][nt], 0, 0, 0);
        accu[1][nt] = __builtin_amdgcn_mfma_f32_16x16x32_bf16(af1, b0, accu[1][nt], 0, 0, 0);
        bf16x8 b1 = *(const bf16x8*)&bg[nt*16 + lr][kc2*32 + kb];
        accg[0][nt] = __builtin_amdgcn_mfma_f32_16x16x32_bf16(af0, b1, accg[0][nt], 0, 0, 0);
        accg[1][nt] = __builtin_amdgcn_mfma_f32_16x16x32_bf16(af1, b1, accg[1][nt], 0, 0, 0);
      }
    }
    __syncthreads();
  }

  const int lr = l & 15;
  #pragma unroll
  for (int mt = 0; mt < 2; ++mt)
    #pragma unroll
    for (int nt = 0; nt < 4; ++nt)
      #pragma unroll
      for (int r = 0; r < 4; ++r){
        int trow = w*32 + mt*16 + (l >> 4)*4 + r;
        s_ub[3 + trow][nt*16 + lr] = f2bf(accu[mt][nt][r]);
      }
  __syncthreads();

  #pragma unroll
  for (int mt = 0; mt < 2; ++mt)
    #pragma unroll
    for (int nt = 0; nt < 4; ++nt)
      #pragma unroll
      for (int r = 0; r < 4; ++r){
        int trow = w*32 + mt*16 + (l >> 4)*4 + r;
        int cl = nt*16 + lr;
        float a0 = s_cb[cl];
        #pragma unroll
        for (int j = 0; j < KW; ++j)
          a0 = fmaf(bf2f(s_ub[trow + j][cl]), s_cw[cl][j], a0);
        float h = siluf(a0);
        float o = siluf(accg[mt][nt][r]) * h;
        Chh[(size_t)(m0 + trow)*DIM + (n0 + cl)] = f2bf(o);
      }
}

// ---- Wout GEMM 64x64: fused comb + resid + per-row ssq partials ------------
__global__ void __launch_bounds__(256) k_gemm_wout(const float* __restrict__ p0,
                                                   const float* __restrict__ p1,
                                                   const unsigned short* __restrict__ Bt,
                                                   const float* __restrict__ y,
                                                   float* __restrict__ x,
                                                   float* __restrict__ rowssq){
  __shared__ unsigned short as[64][72];
  __shared__ unsigned short bs[64][72];
  const int tid = threadIdx.x;
  const int w = tid >> 6, l = tid & 63;
  const int m0 = blockIdx.y*64, n0 = blockIdx.x*64;
  const int ar = tid >> 2, ac = (tid & 3)*16;
  f32x4 acc[4] = {};
  for (int k0 = 0; k0 < DD; k0 += 64){
    #pragma unroll
    for (int j = 0; j < 4; ++j){
      size_t off = (size_t)(m0+ar)*DD + k0 + ac + j*4;
      float4 a = *(const float4*)&p0[off];
      float4 b = *(const float4*)&p1[off];
      a.x += b.x; a.y += b.y; a.z += b.z; a.w += b.w;
      ushort4 u = make_ushort4(f2bf(a.x), f2bf(a.y), f2bf(a.z), f2bf(a.w));
      *(ushort4*)&as[ar][ac + j*4] = u;
    }
    { const bf16x8* src = (const bf16x8*)&Bt[(size_t)(n0+ar)*DD + k0 + ac];
      *(bf16x8*)&bs[ar][ac]   = src[0];
      *(bf16x8*)&bs[ar][ac+8] = src[1];
    }
    __syncthreads();
    const int mr = w*16 + (l & 15);
    const int kb = (l >> 4)*8;
    #pragma unroll
    for (int kc2 = 0; kc2 < 2; ++kc2){
      bf16x8 af = *(const bf16x8*)&as[mr][kc2*32 + kb];
      #pragma unroll
      for (int nt = 0; nt < 4; ++nt){
        bf16x8 bfr = *(const bf16x8*)&bs[nt*16 + (l & 15)][kc2*32 + kb];
        acc[nt] = __builtin_amdgcn_mfma_f32_16x16x32_bf16(af, bfr, acc[nt], 0, 0, 0);
      }
    }
    __syncthreads();
  }
  const int ROWS = BB*TT;
  float ssq[4] = {0.f, 0.f, 0.f, 0.f};
  #pragma unroll
  for (int nt = 0; nt < 4; ++nt){
    int col = n0 + nt*16 + (l & 15);
    #pragma unroll
    for (int r = 0; r < 4; ++r){
      int row = m0 + w*16 + (l >> 4)*4 + r;
      size_t off = (size_t)row*DD + col;
      float nv = x[off] + y[off] + acc[nt][r];
      x[off] = nv;
      ssq[r] = fmaf(nv, nv, ssq[r]);
    }
  }
  #pragma unroll
  for (int r = 0; r < 4; ++r){
    float s = ssq[r];
    s = xor1_add(s); s = xor2_add(s); s = ror4_add(s); s = ror8_add(s);
    if ((l & 15) == 0){
      int row = m0 + w*16 + (l >> 4)*4 + r;
      rowssq[(size_t)blockIdx.x*ROWS + row] = s;
    }
  }
}

// ---------------- sequential delta-memory scan, d-split-16 ----------
// Chain-shaved: vbt = v*btv and dcb = dc*btv precomputed off-chain at
// prefetch; err = fma(-dcb, rrc, vbt) is ONE chain op.
#define SSTEP(T_, WK, RK, PF, VB, DB, DC, BL) { \
  const float vbt = VB, dcb = DB, dcl = DC, blgl = BL; \
  { const int tn_ = ((T_)+2 < 64) ? (T_)+2 : 63; \
    PF = *(const float4*)&s_rk[p][tn_][dbase]; \
    float vraw = bf2f(s_v[p][tn_][vidx]); \
    float4 sc4 = *(const float4*)&s_sc[p][tn_][0]; \
    VB = vraw*sc4.y; DB = sc4.x*sc4.y; DC = sc4.x; BL = sc4.z; } \
  const float err = fmaf(-dcb, rrc, vbt); \
  float rr0=0.f, rr1=0.f; \
  { const float4 rp = WK; const float4 rc = RK; \
    float w0,w1,w2,w3,c0,c1,c2,c3; \
    if (ROT == 0){ w0=rp.x; w1=rp.y; w2=rp.z; w3=rp.w; c0=rc.x; c1=rc.y; c2=rc.z; c3=rc.w; } \
    else { w0=-rp.y; w1=rp.x; w2=-rp.w; w3=rp.z; c0=-rc.y; c1=rc.x; c2=-rc.w; c3=rc.z; } \
    S[0] = fmaf(S[0], dcl, w0*err); rr0 = fmaf(S[0], c0, rr0); \
    S[1] = fmaf(S[1], dcl, w1*err); rr1 = fmaf(S[1], c1, rr1); \
    S[2] = fmaf(S[2], dcl, w2*err); rr0 = fmaf(S[2], c2, rr0); \
    S[3] = fmaf(S[3], dcl, w3*err); rr1 = fmaf(S[3], c3, rr1); } \
  float rr = rr0 + rr1; \
  rr = xor1_add(rr); rr = xor2_add(rr); rr = ror4_add(rr); rr = ror8_add(rr); \
  rrc = rr; \
  if (seg == 0) part[(size_t)(rowchunk + (T_))*DD + h*HDIM + kq4*4 + klocal] = blgl*rr; \
}

template<int ROT>
__device__ __forceinline__ void scan_body(int b, int h, int kq4, int l,
    const unsigned short* __restrict__ vals, const float* __restrict__ rkb,
    const float* __restrict__ scal, float* __restrict__ part,
    float (*s_rk)[64][64], unsigned short (*s_v)[64][8], float (*s_sc)[64][4])
{
  const int seg = l & 15, klocal = l >> 4;
  const int dbase = seg*4;
  const int vidx = (kq4 & 1)*4 + klocal;
  const int kq8 = kq4 >> 1;
  const int rowbase = b*TT;

  float S[4];
  #pragma unroll
  for (int j = 0; j < 4; ++j) S[j] = 0.f;
  const float4 Z = make_float4(0.f,0.f,0.f,0.f);
  float4 rb0 = Z, rb1 = Z, rb2 = Z, rb3 = Z;
  float vb0=0.f, vb1=0.f, db0=0.f, db1=0.f, dc0=0.f, dc1=0.f, bl0=0.f, bl1=0.f;
  float rrc = 0.f;

  auto stage = [&](int c, int pbuf){
    const int r0 = rowbase + c*64;
    #pragma unroll
    for (int i = 0; i < 16; ++i){
      const float* g = rkb + (size_t)(r0 + i*4 + (l>>4))*DD + h*HDIM + (l&15)*4;
      gl_lds16(g, &s_rk[pbuf][i*4][0]);
    }
    { const unsigned short* g = vals + ((size_t)(r0 + l)*MM + ROT)*DD + h*HDIM + kq8*8;
      gl_lds16(g, &s_v[pbuf][0][0]); }
    { const float* g = scal + ((size_t)(r0 + l)*MM + ROT)*(HH*4) + h*4;
      gl_lds16(g, &s_sc[pbuf][0][0]); }
  };

  stage(0, 0);
  for (int c = 0; c < TT/64; ++c){
    const int p = c & 1;
    __syncthreads();
    if (c + 1 < TT/64) stage(c+1, p^1);
    rb0 = *(const float4*)&s_rk[p][0][dbase];
    rb1 = *(const float4*)&s_rk[p][1][dbase];
    { float vraw = bf2f(s_v[p][0][vidx]);
      float4 sc4 = *(const float4*)&s_sc[p][0][0];
      vb0 = vraw*sc4.y; db0 = sc4.x*sc4.y; dc0 = sc4.x; bl0 = sc4.z; }
    { float vraw = bf2f(s_v[p][1][vidx]);
      float4 sc4 = *(const float4*)&s_sc[p][1][0];
      vb1 = vraw*sc4.y; db1 = sc4.x*sc4.y; dc1 = sc4.x; bl1 = sc4.z; }
    const int rowchunk = rowbase + c*64;
    for (int tt = 0; tt < 64; tt += 4){
      SSTEP(tt+0, rb3, rb0, rb2, vb0, db0, dc0, bl0)
      SSTEP(tt+1, rb0, rb1, rb3, vb1, db1, dc1, bl1)
      SSTEP(tt+2, rb1, rb2, rb0, vb0, db0, dc0, bl0)
      SSTEP(tt+3, rb2, rb3, rb1, vb1, db1, dc1, bl1)
    }
  }
}

__global__ void __launch_bounds__(64) k_scan(const unsigned short* __restrict__ vals,
                                             const float* __restrict__ rkb,
                                             const float* __restrict__ scal,
                                             float* __restrict__ partials){
  __shared__ float s_rk[2][64][64];
  __shared__ unsigned short s_v[2][64][8];
  __shared__ float s_sc[2][64][4];
  const int bi = blockIdx.x;
  const int kq4 = bi & 15;
  const int m  = (bi >> 4) & 1;
  const int h  = (bi >> 5) & 3;
  const int b  = bi >> 7;
  float* part = partials + (size_t)m*(BB*TT*DD);
  if (m == 0) scan_body<0>(b, h, kq4, threadIdx.x, vals, rkb, scal, part, s_rk, s_v, s_sc);
  else        scan_body<1>(b, h, kq4, threadIdx.x, vals, rkb, scal, part, s_rk, s_v, s_sc);
}

extern "C" void kernel_launch(void* const* d_in, const int* in_sizes, int n_in,
                              void* d_out, int out_size, void* d_ws, size_t ws_size,
                              hipStream_t stream){
  const int*   ids   = (const int*)d_in[0];
  const float* emb   = (const float*)d_in[1];
  const float* normw = (const float*)d_in[2];
  const float* Wup   = (const float*)d_in[3];
  const float* Wgate = (const float*)d_in[4];
  const float* Wdown = (const float*)d_in[5];
  const float* convw = (const float*)d_in[6];
  const float* convb = (const float*)d_in[7];
  const float* Wv    = (const float*)d_in[8];
  const float* Wg    = (const float*)d_in[9];
  const float* Wb    = (const float*)d_in[10];
  const float* Wa    = (const float*)d_in[11];
  const float* A_log = (const float*)d_in[12];
  const float* dtb   = (const float*)d_in[13];
  const float* Wbl   = (const float*)d_in[14];
  const float* Wout  = (const float*)d_in[15];
  const float* fnw   = (const float*)d_in[16];
  float* out = (float*)d_out;

  const int ROWS = BB*TT;              // 4096
  const size_t MEG = 1u << 20;
  float* ws   = (float*)d_ws;
  float* x    = ws;                        // 1M f32
  unsigned short* nyb = (unsigned short*)(x + MEG);    // 1M bf16
  float* big1 = x + MEG + MEG/2;           // 2M floats
  float* big2 = big1 + 2*MEG;              // 2M f32: partials
  float* y    = big2 + 2*MEG;              // 1M f32
  float* rkb  = y    + MEG;                // 1M f32
  float* scal = rkb  + MEG;                // 128K f32
  float* rowssq = scal + (1u<<17);         // 4*4096 f32
  unsigned short* wbf = (unsigned short*)(rowssq + 4*ROWS);

  unsigned short* gb  = (unsigned short*)(big1 + MEG);   // hh
  unsigned short* valsb = (unsigned short*)big1;

  // merged cvt + embed_norm
  k_init<<<CVTB + ROWS/4, 256, 0, stream>>>(Wup, Wgate, Wdown, Wv, Wout, emb,
                                            normw, fnw, wbf, ids, x, nyb);

  for (int l = 0; l < LL; ++l){
    unsigned short* wl = wbf + (size_t)l*LWB;
    unsigned short* upT   = wl;
    unsigned short* gateT = wl + 131072;
    unsigned short* downT = wl + 262144;
    unsigned short* wvT   = wl + 393216;
    unsigned short* woutT = wl + 524288;

    if (l == 0)
      k_gemm_upc<0><<<dim3(DIM/64, ROWS/128), 256, 0, stream>>>(
          nyb, nullptr, nullptr, upT, gateT, convw + l*DIM*KW, convb + l*DIM, gb);
    else
      k_gemm_upc<1><<<dim3(DIM/64, ROWS/128), 256, 0, stream>>>(
          nullptr, x, rowssq, upT, gateT, convw + l*DIM*KW, convb + l*DIM, gb);
    k_gemm64<2><<<dim3(DD/64, ROWS/64), 256, 0, stream>>>(gb, downT, y, nyb, DD, DIM);
    // merged wv GEMM + fused proj/scal/rk
    k_wvf<<<256 + ROWS/4, 256, 0, stream>>>(nyb, wvT, valsb, y,
                                            Wg + l*DD*HH, Wb + (size_t)l*MM*DD*HH,
                                            Wa + (size_t)l*MM*DD*HH, Wbl + l*DD*HH*MM,
                                            A_log + l*MM*HH, dtb + l*MM*HH, rkb, scal);
    k_scan<<<BB*HH*MM*16, 64, 0, stream>>>(valsb, rkb, scal, big2);
    k_gemm_wout<<<dim3(DD/64, ROWS/64), 256, 0, stream>>>(big2, big2 + MEG, woutT, y, x, rowssq);
  }

  unsigned short* embT = wbf + 2*LWB;   // [272][256] bf16 (fnw folded)
  k_gemmlogit<<<dim3((VV+63)/64, ROWS/64), 256, 0, stream>>>(x, rowssq, embT, out, VV, DD);
}